// Round 18
// baseline (422.414 us; speedup 1.0000x reference)
//
#include <hip/hip_runtime.h>

#define NN 50000
#define NE 800000
#define DIN 256
#define NH 3
#define HC 64
#define DD 192
#define DF 64
#define NB 196   // (NN + 255) / 256

typedef __attribute__((ext_vector_type(8))) short s8bf;            // 8 bf16 bit-patterns
typedef __attribute__((ext_vector_type(8))) unsigned short u16x8;
typedef __attribute__((ext_vector_type(4))) float f32x4;

// ---- fp32 -> bf16 helpers ----
__device__ __forceinline__ unsigned short f2bf(float f) {
    unsigned u = __float_as_uint(f);
    unsigned r = u + 0x7fffu + ((u >> 16) & 1u);   // round-to-nearest-even
    return (unsigned short)(r >> 16);
}
__device__ __forceinline__ float bf2f(unsigned short h) {
    return __uint_as_float(((unsigned)h) << 16);
}
__device__ __forceinline__ void split2(float f, unsigned short& h, unsigned short& l) {
    h = f2bf(f);
    l = f2bf(f - bf2f(h));
}
__device__ __forceinline__ float rl_f(float v, int j) {
    return __int_as_float(__builtin_amdgcn_readlane(__float_as_int(v), j));
}

// ---- split + transpose weights; thread = (k-octet, d): coalesced reads, 16B writes ----
#define W1G (DIN / 8 * DD)       // 6144 groups
#define W2G (DD / 8 * DD)        // 4608
#define WFG (DD / 8 * DF)        // 1536
__global__ __launch_bounds__(256)
void wsplit_all(const float* __restrict__ W1, const float* __restrict__ W2,
                const float* __restrict__ Wf,
                unsigned short* __restrict__ W1hT, unsigned short* __restrict__ W1lT,
                unsigned short* __restrict__ W2hT, unsigned short* __restrict__ W2lT,
                unsigned short* __restrict__ WfhT, unsigned short* __restrict__ WflT) {
    int idx = blockIdx.x * 256 + threadIdx.x;
    const float* W; unsigned short *Wh, *Wl; int K, D, base;
    if (idx < W1G)                  { W = W1; Wh = W1hT; Wl = W1lT; K = DIN; D = DD; base = idx; }
    else if (idx < W1G + W2G)       { W = W2; Wh = W2hT; Wl = W2lT; K = DD;  D = DD; base = idx - W1G; }
    else if (idx < W1G + W2G + WFG) { W = Wf; Wh = WfhT; Wl = WflT; K = DD;  D = DF; base = idx - W1G - W2G; }
    else return;
    int kb = base / D, d = base - kb * D;   // consecutive threads -> consecutive d (coalesced reads)
    u16x8 hv, lv;
#pragma unroll
    for (int q = 0; q < 8; ++q) {
        unsigned short h, l;
        split2(W[(size_t)(kb * 8 + q) * D + d], h, l);
        hv[q] = h; lv[q] = l;
    }
    *(u16x8*)(Wh + (size_t)d * K + kb * 8) = hv;
    *(u16x8*)(Wl + (size_t)d * K + kb * 8) = lv;
}

// ---- LDS full-K-panel bf16-A x split-bf16-B MFMA GEMM; 32 rows/block (grid 2x) ----
// MODE 0: A-source = A1 (fp32)                          -> Yb bf16
// MODE 1: A-source = bn1(relu(A1+bb1)); coefs per-BLOCK -> Yb bf16
// MODE 2: A-source = bn1(..A1..) + bn2(..A2..)          -> Yf fp32 + obias
// DOTS: epilogue computes per-row a_s/a_d -> as4o/ad4o
template<int K, int DOUT, int MODE, bool DOTS>
__global__ __launch_bounds__(256)
void mfma_gemm(const float* __restrict__ A1, const float* __restrict__ A2,
               const float* __restrict__ bb1, const float* __restrict__ S1a_,
               const float* __restrict__ S2a_, const float* __restrict__ g1_,
               const float* __restrict__ be1_,
               const float* __restrict__ bb2, const float* __restrict__ S1b_,
               const float* __restrict__ S2b_, const float* __restrict__ g2_,
               const float* __restrict__ be2_,
               const unsigned short* __restrict__ BhT, const unsigned short* __restrict__ BlT,
               const float* __restrict__ att_s, const float* __restrict__ att_d,
               float4* __restrict__ as4o, float4* __restrict__ ad4o,
               const float* __restrict__ obias, float* __restrict__ Yf,
               unsigned short* __restrict__ Yb, int n) {
    constexpr int NT = DOUT / 64;            // 16-col tiles per wave (192->3, 64->1)
    constexpr int KB8 = K / 8;               // k-octets per row
    constexpr int NCF = (MODE == 2) ? 4 : (MODE == 1 ? 2 : 1);
    __shared__ unsigned short AH[32 * KB8 * 8];   // 16 KB (K=256) / 12 KB (K=192)
    __shared__ float sdots[DOTS ? 4 : 1][32][6];
    __shared__ float cf[NCF][DD];            // per-block BN scale/shift

    const int tid = threadIdx.x;
    const int wave = tid >> 6, lane = tid & 63;
    const int r = lane & 15, kg = lane >> 4;
    const int row0 = blockIdx.x * 32;
    const int col0 = wave * (DOUT / 4);

    // ---- per-block BN coefficient build (192 rsqrt once per block) ----
    if constexpr (MODE >= 1) {
        if (tid < DD) {
            const float invn = 1.0f / NN;
            float mu = S1a_[tid] * invn;
            float var = S2a_[tid] * invn - mu * mu;
            float sc = g1_[tid] * rsqrtf(var + 1e-5f);
            cf[0][tid] = sc;
            cf[1][tid] = be1_[tid] - mu * sc;
            if constexpr (MODE == 2) {
                mu = S1b_[tid] * invn;
                var = S2b_[tid] * invn - mu * mu;
                sc = g2_[tid] * rsqrtf(var + 1e-5f);
                cf[2][tid] = sc;
                cf[3][tid] = be2_[tid] - mu * sc;
            }
        }
        __syncthreads();
    }

    // ---- stage full A panel, 2-stage load pipeline ----
    constexpr int SIT = 32 * KB8 / 256;      // 4 (K=256) / 3 (K=192)
    auto aoff = [&](int i) {
        int idx = tid + i * 256;
        int row = idx / KB8, kb = idx - row * KB8;
        int grow = min(row0 + row, n - 1);
        return (size_t)grow * K + kb * 8;
    };
    float4 cv0, cv1, cu0, cu1;
    {
        size_t o0 = aoff(0);
        cv0 = *(const float4*)(A1 + o0);
        cv1 = *(const float4*)(A1 + o0 + 4);
        if constexpr (MODE == 2) {
            cu0 = *(const float4*)(A2 + o0);
            cu1 = *(const float4*)(A2 + o0 + 4);
        }
    }
#pragma unroll
    for (int i = 0; i < SIT; ++i) {
        float4 nv0, nv1, nu0, nu1;
        if (i + 1 < SIT) {
            size_t on = aoff(i + 1);
            nv0 = *(const float4*)(A1 + on);
            nv1 = *(const float4*)(A1 + on + 4);
            if constexpr (MODE == 2) {
                nu0 = *(const float4*)(A2 + on);
                nu1 = *(const float4*)(A2 + on + 4);
            }
        }
        int idx = tid + i * 256;
        int row = idx / KB8, kb = idx - row * KB8;
        int j = kb * 8;
        float v[8];
        *(float4*)&v[0] = cv0; *(float4*)&v[4] = cv1;
        if constexpr (MODE >= 1) {
#pragma unroll
            for (int q = 0; q < 8; ++q)
                v[q] = fmaxf(v[q] + bb1[j + q], 0.f) * cf[0][j + q] + cf[1][j + q];
        }
        if constexpr (MODE == 2) {
            float u[8];
            *(float4*)&u[0] = cu0; *(float4*)&u[4] = cu1;
#pragma unroll
            for (int q = 0; q < 8; ++q)
                v[q] += fmaxf(u[q] + bb2[j + q], 0.f) * cf[2][j + q] + cf[3][j + q];
        }
        u16x8 hv;
#pragma unroll
        for (int q = 0; q < 8; ++q)
            hv[q] = f2bf(v[q]);
        int sw = kb ^ (row & 7);
        *(u16x8*)&AH[(row * KB8 + sw) * 8] = hv;
        cv0 = nv0; cv1 = nv1;
        if constexpr (MODE == 2) { cu0 = nu0; cu1 = nu1; }
    }
    __syncthreads();

    int boff[NT];
#pragma unroll
    for (int t = 0; t < NT; ++t)
        boff[t] = (col0 + t * 16 + r) * K + kg * 8;

    f32x4 acc[2][NT] = {};

    auto loadB = [&](int k0, s8bf* bh, s8bf* bl) {
#pragma unroll
        for (int t = 0; t < NT; ++t) {
            bh[t] = *(const s8bf*)(BhT + boff[t] + k0);
            bl[t] = *(const s8bf*)(BlT + boff[t] + k0);
        }
    };
    auto loadA = [&](int k0, s8bf* ah) {
        const int kb = k0 / 8 + kg;
#pragma unroll
        for (int g = 0; g < 2; ++g) {
            int row = g * 16 + r;
            int sw = kb ^ (row & 7);
            ah[g] = *(const s8bf*)&AH[(row * KB8 + sw) * 8];
        }
    };

    // ---- K loop, software-pipelined ----
    s8bf bh[NT], bl[NT], ah2[2];
    loadB(0, bh, bl);
    loadA(0, ah2);
#pragma unroll
    for (int k0 = 0; k0 < K; k0 += 32) {
        s8bf nbh[NT], nbl[NT], nah[2];
        if (k0 + 32 < K) {
            loadB(k0 + 32, nbh, nbl);
            loadA(k0 + 32, nah);
        }
#pragma unroll
        for (int g = 0; g < 2; ++g)
#pragma unroll
            for (int t = 0; t < NT; ++t) {
                acc[g][t] = __builtin_amdgcn_mfma_f32_16x16x32_bf16(ah2[g], bh[t], acc[g][t], 0, 0, 0);
                acc[g][t] = __builtin_amdgcn_mfma_f32_16x16x32_bf16(ah2[g], bl[t], acc[g][t], 0, 0, 0);
            }
#pragma unroll
        for (int t = 0; t < NT; ++t) { bh[t] = nbh[t]; bl[t] = nbl[t]; }
#pragma unroll
        for (int g = 0; g < 2; ++g) ah2[g] = nah[g];
    }

    // ---- C write. layout: col = lane&15 (within tile), row = (lane>>4)*4 + reg ----
#pragma unroll
    for (int t = 0; t < NT; ++t) {
        int col = col0 + t * 16 + r;
        float b = (MODE == 2) ? obias[col] : 0.f;
#pragma unroll
        for (int g = 0; g < 2; ++g) {
#pragma unroll
            for (int rr = 0; rr < 4; ++rr) {
                int row = row0 + g * 16 + kg * 4 + rr;
                if (row < n) {
                    if constexpr (MODE == 2)
                        Yf[(size_t)row * DOUT + col] = acc[g][t][rr] + b;
                    else
                        Yb[(size_t)row * DOUT + col] = f2bf(acc[g][t][rr]);
                }
            }
        }
    }

    // ---- fused attention dots epilogue ----
    if constexpr (DOTS) {
        float asv[NT], adv[NT];
        int headt[NT];
#pragma unroll
        for (int t = 0; t < NT; ++t) {
            int col = col0 + t * 16 + r;
            asv[t] = att_s[col];
            adv[t] = att_d[col];
            headt[t] = (col0 + t * 16) >> 6;   // wave-uniform
        }
#pragma unroll
        for (int g = 0; g < 2; ++g) {
#pragma unroll
            for (int rr = 0; rr < 4; ++rr) {
                float rs0 = 0.f, rs1 = 0.f, rs2 = 0.f;
                float rd0 = 0.f, rd1 = 0.f, rd2 = 0.f;
#pragma unroll
                for (int t = 0; t < NT; ++t) {
                    float v = acc[g][t][rr];
                    float s = v * asv[t], dd = v * adv[t];
                    if (headt[t] == 0)      { rs0 += s; rd0 += dd; }
                    else if (headt[t] == 1) { rs1 += s; rd1 += dd; }
                    else                    { rs2 += s; rd2 += dd; }
                }
#pragma unroll
                for (int m = 1; m < 16; m <<= 1) {
                    rs0 += __shfl_xor(rs0, m); rs1 += __shfl_xor(rs1, m); rs2 += __shfl_xor(rs2, m);
                    rd0 += __shfl_xor(rd0, m); rd1 += __shfl_xor(rd1, m); rd2 += __shfl_xor(rd2, m);
                }
                if (r == 0) {
                    int row = g * 16 + kg * 4 + rr;
                    sdots[wave][row][0] = rs0; sdots[wave][row][1] = rs1; sdots[wave][row][2] = rs2;
                    sdots[wave][row][3] = rd0; sdots[wave][row][4] = rd1; sdots[wave][row][5] = rd2;
                }
            }
        }
        __syncthreads();
        if (tid < 32) {
            int row = row0 + tid;
            if (row < n) {
                float s0 = 0.f, s1 = 0.f, s2 = 0.f, d0 = 0.f, d1 = 0.f, d2 = 0.f;
#pragma unroll
                for (int w = 0; w < 4; ++w) {
                    s0 += sdots[w][tid][0]; s1 += sdots[w][tid][1]; s2 += sdots[w][tid][2];
                    d0 += sdots[w][tid][3]; d1 += sdots[w][tid][4]; d2 += sdots[w][tid][5];
                }
                as4o[row] = make_float4(s0, s1, s2, 0.f);
                ad4o[row] = make_float4(d0, d1, d2, 0.f);
            }
        }
    }
}

// ============ CSR build (+ degree buckets for balanced gat scheduling) ============
__global__ void hist_kernel(const int* __restrict__ dst, int* __restrict__ deg, int ne) {
    int e = blockIdx.x * blockDim.x + threadIdx.x;
    if (e < ne) atomicAdd(&deg[dst[e]], 1);
}

// per-256 sums + LDS-aggregated degree-bucket histogram (bucket = 63-min(deg,63))
__global__ __launch_bounds__(256)
void blocksum_kernel(const int* __restrict__ deg, int* __restrict__ bsum,
                     int* __restrict__ dhist) {
    __shared__ int lh[64];
    int tid = threadIdx.x;
    if (tid < 64) lh[tid] = 0;
    __syncthreads();
    int i = blockIdx.x * 256 + tid;
    int v = (i < NN) ? deg[i] : 0;
    if (i < NN) atomicAdd(&lh[63 - min(v, 63)], 1);
    int s = v;
#pragma unroll
    for (int off = 32; off; off >>= 1) s += __shfl_down(s, off);
    __shared__ int ws[4];
    if ((tid & 63) == 0) ws[tid >> 6] = s;
    __syncthreads();
    if (tid == 0) bsum[blockIdx.x] = ws[0] + ws[1] + ws[2] + ws[3];
    if (tid < 64 && lh[tid]) atomicAdd(&dhist[tid], lh[tid]);
}

// scan block sums (256 thr) + exclusive scan of the 64 degree buckets (wave 0)
__global__ __launch_bounds__(256)
void scan_bsums(const int* __restrict__ bsum, int* __restrict__ boff,
                int* __restrict__ rowptr, int* __restrict__ dhist) {
    __shared__ int s[256];
    int t = threadIdx.x;
    int v = (t < NB) ? bsum[t] : 0;
    s[t] = v;
    __syncthreads();
    for (int off = 1; off < 256; off <<= 1) {
        int u = (t >= off) ? s[t - off] : 0;
        __syncthreads();
        s[t] += u;
        __syncthreads();
    }
    if (t < NB) boff[t] = s[t] - v;
    if (t == 255) rowptr[NN] = s[255];
    __syncthreads();
    if (t < 64) {
        int dv = dhist[t];
        int ds = dv;
#pragma unroll
        for (int off = 1; off < 64; off <<= 1) {
            int u = __shfl_up(ds, off);
            if (t >= off) ds += u;
        }
        dhist[t] = ds - dv;    // exclusive base per bucket
    }
}

// rowptr/cursor expand + two-level low-contention perm scatter (desc degree)
__global__ __launch_bounds__(256)
void expand_kernel(const int* __restrict__ deg, const int* __restrict__ boff,
                   int* __restrict__ rowptr, int* __restrict__ cursor,
                   int* __restrict__ dhist, int* __restrict__ perm) {
    __shared__ int s[256];
    __shared__ int lcnt[64], lbase[64];
    int t = threadIdx.x;
    int i = blockIdx.x * 256 + t;
    int v = (i < NN) ? deg[i] : 0;
    if (t < 64) lcnt[t] = 0;
    s[t] = v;
    __syncthreads();
    for (int off = 1; off < 256; off <<= 1) {
        int u = (t >= off) ? s[t - off] : 0;
        __syncthreads();
        s[t] += u;
        __syncthreads();
    }
    int b = 63 - min(v, 63);
    int myidx = 0;
    if (i < NN) myidx = atomicAdd(&lcnt[b], 1);
    __syncthreads();
    if (t < 64 && lcnt[t]) lbase[t] = atomicAdd(&dhist[t], lcnt[t]);
    __syncthreads();
    if (i < NN) {
        int excl = s[t] - v + boff[blockIdx.x];
        rowptr[i] = excl;
        cursor[i] = excl;
        perm[lbase[b] + myidx] = i;
    }
}

__global__ void scatter_kernel(const int* __restrict__ src, const int* __restrict__ dst,
                               int* __restrict__ cursor, int* __restrict__ csr_src, int ne) {
    int e = blockIdx.x * blockDim.x + threadIdx.x;
    if (e >= ne) return;
    int d = dst[e];
    int pos = atomicAdd(&cursor[d], 1);
    csr_src[pos] = src[e];
}

// ============ GAT gather: 8-edge batched; degree-sorted node order ============
__global__ __launch_bounds__(256)
void gat_gather(const unsigned short* __restrict__ xf,
                const float4* __restrict__ as4, const float4* __restrict__ ad4,
                const int* __restrict__ rowptr, const int* __restrict__ csr_src,
                const int* __restrict__ perm, float* __restrict__ outp) {
    const int d = perm[blockIdx.x * 4 + (threadIdx.x >> 6)];   // grid*4 == NN exactly
    const int lane = threadIdx.x & 63;
    const int beg = rowptr[d], end = rowptr[d + 1];
    const float4 adv = ad4[d];

    float a0 = 0.f, a1 = 0.f, a2 = 0.f;
    float den0 = 0.f, den1 = 0.f, den2 = 0.f;

    for (int base = beg; base < end; base += 64) {
        const int nb = min(64, end - base);
        int sl = 0;
        float w0 = 0.f, w1 = 0.f, w2 = 0.f;
        if (lane < nb) {
            sl = csr_src[base + lane];
            float4 av = as4[sl];               // one 16B gather per lane
            float e0 = av.x + adv.x;
            float e1 = av.y + adv.y;
            float e2 = av.z + adv.z;
            e0 = e0 > 0.f ? e0 : 0.2f * e0;
            e1 = e1 > 0.f ? e1 : 0.2f * e1;
            e2 = e2 > 0.f ? e2 : 0.2f * e2;
            w0 = __expf(e0); w1 = __expf(e1); w2 = __expf(e2);
        }
        float r0 = w0, r1 = w1, r2 = w2;
#pragma unroll
        for (int off = 1; off < 64; off <<= 1) {
            r0 += __shfl_xor(r0, off);
            r1 += __shfl_xor(r1, off);
            r2 += __shfl_xor(r2, off);
        }
        den0 += r0; den1 += r1; den2 += r2;

        int j = 0;
        for (; j + 8 <= nb; j += 8) {
            const unsigned short* xp[8];
            float uw0[8], uw1[8], uw2[8];
#pragma unroll
            for (int k = 0; k < 8; ++k) {
                int s = __builtin_amdgcn_readlane(sl, j + k);
                xp[k] = xf + (size_t)s * DD;
                uw0[k] = rl_f(w0, j + k);
                uw1[k] = rl_f(w1, j + k);
                uw2[k] = rl_f(w2, j + k);
            }
            unsigned short f0[8], f1[8], f2[8];
#pragma unroll
            for (int k = 0; k < 8; ++k) {
                f0[k] = xp[k][lane];
                f1[k] = xp[k][64 + lane];
                f2[k] = xp[k][128 + lane];
            }
#pragma unroll
            for (int k = 0; k < 8; ++k) {
                a0 = fmaf(bf2f(f0[k]), uw0[k], a0);
                a1 = fmaf(bf2f(f1[k]), uw1[k], a1);
                a2 = fmaf(bf2f(f2[k]), uw2[k], a2);
            }
        }
        for (; j < nb; ++j) {
            int s = __builtin_amdgcn_readlane(sl, j);
            float u0 = rl_f(w0, j), u1 = rl_f(w1, j), u2 = rl_f(w2, j);
            const unsigned short* xp = xf + (size_t)s * DD;
            a0 = fmaf(bf2f(xp[lane]),       u0, a0);
            a1 = fmaf(bf2f(xp[64 + lane]),  u1, a1);
            a2 = fmaf(bf2f(xp[128 + lane]), u2, a2);
        }
    }
    size_t o = (size_t)d * DD + lane;
    outp[o]       = a0 / (den0 + 1e-16f);
    outp[o + 64]  = a1 / (den1 + 1e-16f);
    outp[o + 128] = a2 / (den2 + 1e-16f);
}

// ---- BN pass 1: 64 rows/block (782 blocks) ----
__global__ __launch_bounds__(192)
void bn_stats(const float* __restrict__ hbuf, const float* __restrict__ bias,
              float* __restrict__ s1, float* __restrict__ s2, int n) {
    int j = threadIdx.x;
    float b = bias[j];
    int r0 = blockIdx.x * 64;
    int r1 = min(r0 + 64, n);
    float a = 0.f, q = 0.f;
    for (int r = r0; r < r1; ++r) {
        float v = hbuf[(size_t)r * DD + j] + b;
        v = fmaxf(v, 0.f);
        a += v; q += v * v;
    }
    atomicAdd(&s1[j], a);
    atomicAdd(&s2[j], q);
}

extern "C" void kernel_launch(void* const* d_in, const int* in_sizes, int n_in,
                              void* d_out, int out_size, void* d_ws, size_t ws_size,
                              hipStream_t stream) {
    const float* x   = (const float*)d_in[0];
    const float* W1  = (const float*)d_in[1];
    const float* as1 = (const float*)d_in[2];
    const float* ad1 = (const float*)d_in[3];
    const float* b1  = (const float*)d_in[4];
    const float* g1  = (const float*)d_in[5];
    const float* be1 = (const float*)d_in[6];
    const float* W2  = (const float*)d_in[7];
    const float* as2 = (const float*)d_in[8];
    const float* ad2 = (const float*)d_in[9];
    const float* b2  = (const float*)d_in[10];
    const float* g2  = (const float*)d_in[11];
    const float* be2 = (const float*)d_in[12];
    const float* Wf  = (const float*)d_in[13];
    const float* bf  = (const float*)d_in[14];
    const int*   ei  = (const int*)d_in[15];
    const int* src = ei;
    const int* dst = ei + NE;
    float* out = (float*)d_out;

    float* ws = (float*)d_ws;
    float* CB1 = ws;                          // [N,192]
    float* CB2 = CB1 + (size_t)NN * DD;       // [N,192]
    float4* AS4 = (float4*)(CB2 + (size_t)NN * DD);   // [N] float4
    float4* AD4 = AS4 + NN;                   // [N] float4
    int* DEG   = (int*)(AD4 + NN);            // [N]   -- memset covers DEG..DHIST
    float* S1a = (float*)(DEG + NN);          // [192] x4 stats
    float* S2a = S1a + DD;
    float* S1b = S2a + DD;
    float* S2b = S1b + DD;
    int* DHIST  = (int*)(S2b + DD);           // [64] degree buckets
    int* ROWPTR = DHIST + 64;                 // [N+1]
    int* CURSOR = ROWPTR + NN + 1;            // [N]
    int* PERM   = CURSOR + NN;                // [N]
    int* BSUM   = PERM + NN;                  // [NB]
    int* BOFF   = BSUM + NB;                  // [NB]
    int* CSRS   = BOFF + NB;                  // [E]
    unsigned short* R    = (unsigned short*)(CSRS + NE);
    unsigned short* Abf  = R;                          // [N,192] bf16 features
    unsigned short* W1hT = Abf + (size_t)NN * DD;      // [192,256]
    unsigned short* W1lT = W1hT + DIN * DD;
    unsigned short* W2hT = W1lT + DIN * DD;            // [192,192]
    unsigned short* W2lT = W2hT + DD * DD;
    unsigned short* WfhT = W2lT + DD * DD;             // [64,192]
    unsigned short* WflT = WfhT + DD * DF;

    const int edge_grid = (NE + 255) / 256;
    const int gemm_grid = (NN + 31) / 32;
    const int gat_grid  = NN / 4;             // 12500, exact
    const int bns_grid  = (NN + 63) / 64;
    const int wsp_grid  = (W1G + W2G + WFG + 255) / 256;

    // ---- one memset: DEG + four BN stat vectors + DHIST (contiguous) ----
    hipMemsetAsync(DEG, 0, (size_t)NN * 4 + 4 * DD * 4 + 64 * 4, stream);

    // ---- CSR build + degree-sorted perm (once) ----
    hist_kernel<<<edge_grid, 256, 0, stream>>>(dst, DEG, NE);
    blocksum_kernel<<<NB, 256, 0, stream>>>(DEG, BSUM, DHIST);
    scan_bsums<<<1, 256, 0, stream>>>(BSUM, BOFF, ROWPTR, DHIST);
    expand_kernel<<<NB, 256, 0, stream>>>(DEG, BOFF, ROWPTR, CURSOR, DHIST, PERM);
    scatter_kernel<<<edge_grid, 256, 0, stream>>>(src, dst, CURSOR, CSRS, NE);

    // ---- weight splits ----
    wsplit_all<<<wsp_grid, 256, 0, stream>>>(W1, W2, Wf, W1hT, W1lT, W2hT, W2lT, WfhT, WflT);

    // ================= layer 1 (dots fused) =================
    mfma_gemm<DIN, DD, 0, true><<<gemm_grid, 256, 0, stream>>>(
        x, nullptr,
        nullptr, nullptr, nullptr, nullptr, nullptr,
        nullptr, nullptr, nullptr, nullptr, nullptr,
        W1hT, W1lT, as1, ad1, AS4, AD4, nullptr, nullptr, Abf, NN);
    gat_gather<<<gat_grid, 256, 0, stream>>>(Abf, AS4, AD4, ROWPTR, CSRS, PERM, CB1);
    bn_stats<<<bns_grid, 192, 0, stream>>>(CB1, b1, S1a, S2a, NN);

    // ================= layer 2 (BN1 per-block + dots fused) =================
    mfma_gemm<DD, DD, 1, true><<<gemm_grid, 256, 0, stream>>>(
        CB1, nullptr,
        b1, S1a, S2a, g1, be1,
        nullptr, nullptr, nullptr, nullptr, nullptr,
        W2hT, W2lT, as2, ad2, AS4, AD4, nullptr, nullptr, Abf, NN);
    gat_gather<<<gat_grid, 256, 0, stream>>>(Abf, AS4, AD4, ROWPTR, CSRS, PERM, CB2);
    bn_stats<<<bns_grid, 192, 0, stream>>>(CB2, b2, S1b, S2b, NN);

    // ====== final: out = (bn1(h1) + bn2(h2)) @ Wf + bf (BN per-block in staging) ======
    mfma_gemm<DD, DF, 2, false><<<gemm_grid, 256, 0, stream>>>(
        CB1, CB2,
        b1, S1a, S2a, g1, be1,
        b2, S1b, S2b, g2, be2,
        WfhT, WflT, nullptr, nullptr, nullptr, nullptr, bf, out, nullptr, NN);
}

// Round 19
// 401.609 us; speedup vs baseline: 1.0518x; 1.0518x over previous
//
#include <hip/hip_runtime.h>

#define NN 50000
#define NE 800000
#define DIN 256
#define NH 3
#define HC 64
#define DD 192
#define DF 64
#define NB 196   // (NN + 255) / 256

typedef __attribute__((ext_vector_type(8))) short s8bf;            // 8 bf16 bit-patterns
typedef __attribute__((ext_vector_type(8))) unsigned short u16x8;
typedef __attribute__((ext_vector_type(4))) float f32x4;

// ---- fp32 -> bf16 helpers ----
__device__ __forceinline__ unsigned short f2bf(float f) {
    unsigned u = __float_as_uint(f);
    unsigned r = u + 0x7fffu + ((u >> 16) & 1u);   // round-to-nearest-even
    return (unsigned short)(r >> 16);
}
__device__ __forceinline__ float bf2f(unsigned short h) {
    return __uint_as_float(((unsigned)h) << 16);
}
__device__ __forceinline__ void split2(float f, unsigned short& h, unsigned short& l) {
    h = f2bf(f);
    l = f2bf(f - bf2f(h));
}
__device__ __forceinline__ float rl_f(float v, int j) {
    return __int_as_float(__builtin_amdgcn_readlane(__float_as_int(v), j));
}

// ---- split + transpose weights; thread = (k-octet, d): coalesced reads, 16B writes ----
#define W1G (DIN / 8 * DD)       // 6144 groups
#define W2G (DD / 8 * DD)        // 4608
#define WFG (DD / 8 * DF)        // 1536
__global__ __launch_bounds__(256)
void wsplit_all(const float* __restrict__ W1, const float* __restrict__ W2,
                const float* __restrict__ Wf,
                unsigned short* __restrict__ W1hT, unsigned short* __restrict__ W1lT,
                unsigned short* __restrict__ W2hT, unsigned short* __restrict__ W2lT,
                unsigned short* __restrict__ WfhT, unsigned short* __restrict__ WflT) {
    int idx = blockIdx.x * 256 + threadIdx.x;
    const float* W; unsigned short *Wh, *Wl; int K, D, base;
    if (idx < W1G)                  { W = W1; Wh = W1hT; Wl = W1lT; K = DIN; D = DD; base = idx; }
    else if (idx < W1G + W2G)       { W = W2; Wh = W2hT; Wl = W2lT; K = DD;  D = DD; base = idx - W1G; }
    else if (idx < W1G + W2G + WFG) { W = Wf; Wh = WfhT; Wl = WflT; K = DD;  D = DF; base = idx - W1G - W2G; }
    else return;
    int kb = base / D, d = base - kb * D;   // consecutive threads -> consecutive d (coalesced reads)
    u16x8 hv, lv;
#pragma unroll
    for (int q = 0; q < 8; ++q) {
        unsigned short h, l;
        split2(W[(size_t)(kb * 8 + q) * D + d], h, l);
        hv[q] = h; lv[q] = l;
    }
    *(u16x8*)(Wh + (size_t)d * K + kb * 8) = hv;
    *(u16x8*)(Wl + (size_t)d * K + kb * 8) = lv;
}

// ---- LDS full-K-panel bf16-A x split-bf16-B MFMA GEMM; pipelined; bn_fin folded ----
// MODE 0: A-source = A1 (fp32)                          -> Yb bf16
// MODE 1: A-source = bn1(relu(A1+bb1)); coefs per-BLOCK -> Yb bf16
// MODE 2: A-source = bn1(..A1..) + bn2(..A2..)          -> Yf fp32 + obias
// DOTS: epilogue computes per-row a_s/a_d -> as4o/ad4o
template<int K, int DOUT, int MODE, bool DOTS>
__global__ __launch_bounds__(256)
void mfma_gemm(const float* __restrict__ A1, const float* __restrict__ A2,
               const float* __restrict__ bb1, const float* __restrict__ S1a_,
               const float* __restrict__ S2a_, const float* __restrict__ g1_,
               const float* __restrict__ be1_,
               const float* __restrict__ bb2, const float* __restrict__ S1b_,
               const float* __restrict__ S2b_, const float* __restrict__ g2_,
               const float* __restrict__ be2_,
               const unsigned short* __restrict__ BhT, const unsigned short* __restrict__ BlT,
               const float* __restrict__ att_s, const float* __restrict__ att_d,
               float4* __restrict__ as4o, float4* __restrict__ ad4o,
               const float* __restrict__ obias, float* __restrict__ Yf,
               unsigned short* __restrict__ Yb, int n) {
    constexpr int NT = DOUT / 64;            // 16-col tiles per wave (192->3, 64->1)
    constexpr int KB8 = K / 8;               // k-octets per row
    constexpr int NCF = (MODE == 2) ? 4 : (MODE == 1 ? 2 : 1);
    __shared__ unsigned short AH[64 * KB8 * 8];   // 32 KB (K=256) / 24 KB (K=192)
    __shared__ float sdots[DOTS ? 4 : 1][64][6];
    __shared__ float cf[NCF][DD];            // per-block BN scale/shift

    const int tid = threadIdx.x;
    const int wave = tid >> 6, lane = tid & 63;
    const int r = lane & 15, kg = lane >> 4;
    const int row0 = blockIdx.x * 64;
    const int col0 = wave * (DOUT / 4);

    // ---- per-block BN coefficient build (192 rsqrt once per block) ----
    if constexpr (MODE >= 1) {
        if (tid < DD) {
            const float invn = 1.0f / NN;
            float mu = S1a_[tid] * invn;
            float var = S2a_[tid] * invn - mu * mu;
            float sc = g1_[tid] * rsqrtf(var + 1e-5f);
            cf[0][tid] = sc;
            cf[1][tid] = be1_[tid] - mu * sc;
            if constexpr (MODE == 2) {
                mu = S1b_[tid] * invn;
                var = S2b_[tid] * invn - mu * mu;
                sc = g2_[tid] * rsqrtf(var + 1e-5f);
                cf[2][tid] = sc;
                cf[3][tid] = be2_[tid] - mu * sc;
            }
        }
        __syncthreads();
    }

    // ---- stage full A panel, 2-stage load pipeline ----
    constexpr int SIT = 64 * KB8 / 256;      // 8 (K=256) / 6 (K=192)
    auto aoff = [&](int i) {
        int idx = tid + i * 256;
        int row = idx / KB8, kb = idx - row * KB8;
        int grow = min(row0 + row, n - 1);
        return (size_t)grow * K + kb * 8;
    };
    float4 cv0, cv1, cu0, cu1;
    {
        size_t o0 = aoff(0);
        cv0 = *(const float4*)(A1 + o0);
        cv1 = *(const float4*)(A1 + o0 + 4);
        if constexpr (MODE == 2) {
            cu0 = *(const float4*)(A2 + o0);
            cu1 = *(const float4*)(A2 + o0 + 4);
        }
    }
#pragma unroll
    for (int i = 0; i < SIT; ++i) {
        float4 nv0, nv1, nu0, nu1;
        if (i + 1 < SIT) {
            size_t on = aoff(i + 1);
            nv0 = *(const float4*)(A1 + on);
            nv1 = *(const float4*)(A1 + on + 4);
            if constexpr (MODE == 2) {
                nu0 = *(const float4*)(A2 + on);
                nu1 = *(const float4*)(A2 + on + 4);
            }
        }
        int idx = tid + i * 256;
        int row = idx / KB8, kb = idx - row * KB8;
        int j = kb * 8;
        float v[8];
        *(float4*)&v[0] = cv0; *(float4*)&v[4] = cv1;
        if constexpr (MODE >= 1) {
#pragma unroll
            for (int q = 0; q < 8; ++q)
                v[q] = fmaxf(v[q] + bb1[j + q], 0.f) * cf[0][j + q] + cf[1][j + q];
        }
        if constexpr (MODE == 2) {
            float u[8];
            *(float4*)&u[0] = cu0; *(float4*)&u[4] = cu1;
#pragma unroll
            for (int q = 0; q < 8; ++q)
                v[q] += fmaxf(u[q] + bb2[j + q], 0.f) * cf[2][j + q] + cf[3][j + q];
        }
        u16x8 hv;
#pragma unroll
        for (int q = 0; q < 8; ++q)
            hv[q] = f2bf(v[q]);
        int sw = kb ^ (row & 7);
        *(u16x8*)&AH[(row * KB8 + sw) * 8] = hv;
        cv0 = nv0; cv1 = nv1;
        if constexpr (MODE == 2) { cu0 = nu0; cu1 = nu1; }
    }
    __syncthreads();                          // the only staging barrier

    int boff[NT];
#pragma unroll
    for (int t = 0; t < NT; ++t)
        boff[t] = (col0 + t * 16 + r) * K + kg * 8;

    f32x4 acc[4][NT] = {};

    auto loadB = [&](int k0, s8bf* bh, s8bf* bl) {
#pragma unroll
        for (int t = 0; t < NT; ++t) {
            bh[t] = *(const s8bf*)(BhT + boff[t] + k0);
            bl[t] = *(const s8bf*)(BlT + boff[t] + k0);
        }
    };
    auto loadA = [&](int k0, s8bf* ah) {
        const int kb = k0 / 8 + kg;
#pragma unroll
        for (int g = 0; g < 4; ++g) {
            int row = g * 16 + r;
            int sw = kb ^ (row & 7);
            ah[g] = *(const s8bf*)&AH[(row * KB8 + sw) * 8];
        }
    };

    // ---- K loop, software-pipelined: prefetch (B global, A LDS) over MFMAs ----
    s8bf bh[NT], bl[NT], ah4[4];
    loadB(0, bh, bl);
    loadA(0, ah4);
#pragma unroll
    for (int k0 = 0; k0 < K; k0 += 32) {
        s8bf nbh[NT], nbl[NT], nah[4];
        if (k0 + 32 < K) {
            loadB(k0 + 32, nbh, nbl);
            loadA(k0 + 32, nah);
        }
#pragma unroll
        for (int g = 0; g < 4; ++g)
#pragma unroll
            for (int t = 0; t < NT; ++t) {
                acc[g][t] = __builtin_amdgcn_mfma_f32_16x16x32_bf16(ah4[g], bh[t], acc[g][t], 0, 0, 0);
                acc[g][t] = __builtin_amdgcn_mfma_f32_16x16x32_bf16(ah4[g], bl[t], acc[g][t], 0, 0, 0);
            }
#pragma unroll
        for (int t = 0; t < NT; ++t) { bh[t] = nbh[t]; bl[t] = nbl[t]; }
#pragma unroll
        for (int g = 0; g < 4; ++g) ah4[g] = nah[g];
    }

    // ---- C write. layout: col = lane&15 (within tile), row = (lane>>4)*4 + reg ----
#pragma unroll
    for (int t = 0; t < NT; ++t) {
        int col = col0 + t * 16 + r;
        float b = (MODE == 2) ? obias[col] : 0.f;
#pragma unroll
        for (int g = 0; g < 4; ++g) {
#pragma unroll
            for (int rr = 0; rr < 4; ++rr) {
                int row = row0 + g * 16 + kg * 4 + rr;
                if (row < n) {
                    if constexpr (MODE == 2)
                        Yf[(size_t)row * DOUT + col] = acc[g][t][rr] + b;
                    else
                        Yb[(size_t)row * DOUT + col] = f2bf(acc[g][t][rr]);
                }
            }
        }
    }

    // ---- fused attention dots epilogue ----
    if constexpr (DOTS) {
        float asv[NT], adv[NT];
        int headt[NT];
#pragma unroll
        for (int t = 0; t < NT; ++t) {
            int col = col0 + t * 16 + r;
            asv[t] = att_s[col];
            adv[t] = att_d[col];
            headt[t] = (col0 + t * 16) >> 6;   // wave-uniform
        }
#pragma unroll
        for (int g = 0; g < 4; ++g) {
#pragma unroll
            for (int rr = 0; rr < 4; ++rr) {
                float rs0 = 0.f, rs1 = 0.f, rs2 = 0.f;
                float rd0 = 0.f, rd1 = 0.f, rd2 = 0.f;
#pragma unroll
                for (int t = 0; t < NT; ++t) {
                    float v = acc[g][t][rr];
                    float s = v * asv[t], dd = v * adv[t];
                    if (headt[t] == 0)      { rs0 += s; rd0 += dd; }
                    else if (headt[t] == 1) { rs1 += s; rd1 += dd; }
                    else                    { rs2 += s; rd2 += dd; }
                }
#pragma unroll
                for (int m = 1; m < 16; m <<= 1) {
                    rs0 += __shfl_xor(rs0, m); rs1 += __shfl_xor(rs1, m); rs2 += __shfl_xor(rs2, m);
                    rd0 += __shfl_xor(rd0, m); rd1 += __shfl_xor(rd1, m); rd2 += __shfl_xor(rd2, m);
                }
                if (r == 0) {
                    int row = g * 16 + kg * 4 + rr;
                    sdots[wave][row][0] = rs0; sdots[wave][row][1] = rs1; sdots[wave][row][2] = rs2;
                    sdots[wave][row][3] = rd0; sdots[wave][row][4] = rd1; sdots[wave][row][5] = rd2;
                }
            }
        }
        __syncthreads();
        if (tid < 64) {
            int row = row0 + tid;
            if (row < n) {
                float s0 = 0.f, s1 = 0.f, s2 = 0.f, d0 = 0.f, d1 = 0.f, d2 = 0.f;
#pragma unroll
                for (int w = 0; w < 4; ++w) {
                    s0 += sdots[w][tid][0]; s1 += sdots[w][tid][1]; s2 += sdots[w][tid][2];
                    d0 += sdots[w][tid][3]; d1 += sdots[w][tid][4]; d2 += sdots[w][tid][5];
                }
                as4o[row] = make_float4(s0, s1, s2, 0.f);
                ad4o[row] = make_float4(d0, d1, d2, 0.f);
            }
        }
    }
}

// ============ CSR build ============
__global__ void hist_kernel(const int* __restrict__ dst, int* __restrict__ deg, int ne) {
    int e = blockIdx.x * blockDim.x + threadIdx.x;
    if (e < ne) atomicAdd(&deg[dst[e]], 1);
}

__global__ __launch_bounds__(256)
void blocksum_kernel(const int* __restrict__ deg, int* __restrict__ bsum) {
    int i = blockIdx.x * 256 + threadIdx.x;
    int v = (i < NN) ? deg[i] : 0;
#pragma unroll
    for (int off = 32; off; off >>= 1) v += __shfl_down(v, off);
    __shared__ int ws[4];
    if ((threadIdx.x & 63) == 0) ws[threadIdx.x >> 6] = v;
    __syncthreads();
    if (threadIdx.x == 0) bsum[blockIdx.x] = ws[0] + ws[1] + ws[2] + ws[3];
}

__global__ __launch_bounds__(256)
void scan_bsums(const int* __restrict__ bsum, int* __restrict__ boff,
                int* __restrict__ rowptr) {
    __shared__ int s[256];
    int t = threadIdx.x;
    int v = (t < NB) ? bsum[t] : 0;
    s[t] = v;
    __syncthreads();
    for (int off = 1; off < 256; off <<= 1) {
        int u = (t >= off) ? s[t - off] : 0;
        __syncthreads();
        s[t] += u;
        __syncthreads();
    }
    if (t < NB) boff[t] = s[t] - v;
    if (t == 255) rowptr[NN] = s[255];
}

__global__ __launch_bounds__(256)
void expand_kernel(const int* __restrict__ deg, const int* __restrict__ boff,
                   int* __restrict__ rowptr, int* __restrict__ cursor) {
    __shared__ int s[256];
    int t = threadIdx.x;
    int i = blockIdx.x * 256 + t;
    int v = (i < NN) ? deg[i] : 0;
    s[t] = v;
    __syncthreads();
    for (int off = 1; off < 256; off <<= 1) {
        int u = (t >= off) ? s[t - off] : 0;
        __syncthreads();
        s[t] += u;
        __syncthreads();
    }
    if (i < NN) {
        int excl = s[t] - v + boff[blockIdx.x];
        rowptr[i] = excl;
        cursor[i] = excl;
    }
}

__global__ void scatter_kernel(const int* __restrict__ src, const int* __restrict__ dst,
                               int* __restrict__ cursor, int* __restrict__ csr_src, int ne) {
    int e = blockIdx.x * blockDim.x + threadIdx.x;
    if (e >= ne) return;
    int d = dst[e];
    int pos = atomicAdd(&cursor[d], 1);
    csr_src[pos] = src[e];
}

// ============ GAT gather: 8-edge batched loads for HBM-latency hiding ============
__global__ __launch_bounds__(256)
void gat_gather(const unsigned short* __restrict__ xf,
                const float4* __restrict__ as4, const float4* __restrict__ ad4,
                const int* __restrict__ rowptr, const int* __restrict__ csr_src,
                float* __restrict__ outp) {
    int d = blockIdx.x * 4 + (threadIdx.x >> 6);
    if (d >= NN) return;
    const int lane = threadIdx.x & 63;
    const int beg = rowptr[d], end = rowptr[d + 1];
    const float4 adv = ad4[d];

    float a0 = 0.f, a1 = 0.f, a2 = 0.f;
    float den0 = 0.f, den1 = 0.f, den2 = 0.f;

    for (int base = beg; base < end; base += 64) {
        const int nb = min(64, end - base);
        int sl = 0;
        float w0 = 0.f, w1 = 0.f, w2 = 0.f;
        if (lane < nb) {
            sl = csr_src[base + lane];
            float4 av = as4[sl];               // one 16B gather per lane
            float e0 = av.x + adv.x;
            float e1 = av.y + adv.y;
            float e2 = av.z + adv.z;
            e0 = e0 > 0.f ? e0 : 0.2f * e0;
            e1 = e1 > 0.f ? e1 : 0.2f * e1;
            e2 = e2 > 0.f ? e2 : 0.2f * e2;
            w0 = __expf(e0); w1 = __expf(e1); w2 = __expf(e2);
        }
        float r0 = w0, r1 = w1, r2 = w2;
#pragma unroll
        for (int off = 1; off < 64; off <<= 1) {
            r0 += __shfl_xor(r0, off);
            r1 += __shfl_xor(r1, off);
            r2 += __shfl_xor(r2, off);
        }
        den0 += r0; den1 += r1; den2 += r2;

        int j = 0;
        for (; j + 8 <= nb; j += 8) {
            const unsigned short* xp[8];
            float uw0[8], uw1[8], uw2[8];
#pragma unroll
            for (int k = 0; k < 8; ++k) {
                int s = __builtin_amdgcn_readlane(sl, j + k);
                xp[k] = xf + (size_t)s * DD;
                uw0[k] = rl_f(w0, j + k);
                uw1[k] = rl_f(w1, j + k);
                uw2[k] = rl_f(w2, j + k);
            }
            unsigned short f0[8], f1[8], f2[8];
#pragma unroll
            for (int k = 0; k < 8; ++k) {
                f0[k] = xp[k][lane];
                f1[k] = xp[k][64 + lane];
                f2[k] = xp[k][128 + lane];
            }
#pragma unroll
            for (int k = 0; k < 8; ++k) {
                a0 = fmaf(bf2f(f0[k]), uw0[k], a0);
                a1 = fmaf(bf2f(f1[k]), uw1[k], a1);
                a2 = fmaf(bf2f(f2[k]), uw2[k], a2);
            }
        }
        for (; j < nb; ++j) {
            int s = __builtin_amdgcn_readlane(sl, j);
            float u0 = rl_f(w0, j), u1 = rl_f(w1, j), u2 = rl_f(w2, j);
            const unsigned short* xp = xf + (size_t)s * DD;
            a0 = fmaf(bf2f(xp[lane]),       u0, a0);
            a1 = fmaf(bf2f(xp[64 + lane]),  u1, a1);
            a2 = fmaf(bf2f(xp[128 + lane]), u2, a2);
        }
    }
    size_t o = (size_t)d * DD + lane;
    outp[o]       = a0 / (den0 + 1e-16f);
    outp[o + 64]  = a1 / (den1 + 1e-16f);
    outp[o + 128] = a2 / (den2 + 1e-16f);
}

// ---- BN pass 1: 64 rows/block (782 blocks) for latency hiding ----
__global__ __launch_bounds__(192)
void bn_stats(const float* __restrict__ hbuf, const float* __restrict__ bias,
              float* __restrict__ s1, float* __restrict__ s2, int n) {
    int j = threadIdx.x;
    float b = bias[j];
    int r0 = blockIdx.x * 64;
    int r1 = min(r0 + 64, n);
    float a = 0.f, q = 0.f;
    for (int r = r0; r < r1; ++r) {
        float v = hbuf[(size_t)r * DD + j] + b;
        v = fmaxf(v, 0.f);
        a += v; q += v * v;
    }
    atomicAdd(&s1[j], a);
    atomicAdd(&s2[j], q);
}

extern "C" void kernel_launch(void* const* d_in, const int* in_sizes, int n_in,
                              void* d_out, int out_size, void* d_ws, size_t ws_size,
                              hipStream_t stream) {
    const float* x   = (const float*)d_in[0];
    const float* W1  = (const float*)d_in[1];
    const float* as1 = (const float*)d_in[2];
    const float* ad1 = (const float*)d_in[3];
    const float* b1  = (const float*)d_in[4];
    const float* g1  = (const float*)d_in[5];
    const float* be1 = (const float*)d_in[6];
    const float* W2  = (const float*)d_in[7];
    const float* as2 = (const float*)d_in[8];
    const float* ad2 = (const float*)d_in[9];
    const float* b2  = (const float*)d_in[10];
    const float* g2  = (const float*)d_in[11];
    const float* be2 = (const float*)d_in[12];
    const float* Wf  = (const float*)d_in[13];
    const float* bf  = (const float*)d_in[14];
    const int*   ei  = (const int*)d_in[15];
    const int* src = ei;
    const int* dst = ei + NE;
    float* out = (float*)d_out;

    float* ws = (float*)d_ws;
    float* CB1 = ws;                          // [N,192]
    float* CB2 = CB1 + (size_t)NN * DD;       // [N,192]
    float4* AS4 = (float4*)(CB2 + (size_t)NN * DD);   // [N] float4
    float4* AD4 = AS4 + NN;                   // [N] float4
    int* DEG   = (int*)(AD4 + NN);            // [N]  (zeroed together with stats)
    float* S1a = (float*)(DEG + NN);          // [192] x4 stats
    float* S2a = S1a + DD;
    float* S1b = S2a + DD;
    float* S2b = S1b + DD;
    float* SC1 = S2b + DD;                    // unused (layout stability)
    float* SH1 = SC1 + DD;
    float* SC2 = SH1 + DD;
    float* SH2 = SC2 + DD;
    int* ROWPTR = (int*)(SH2 + DD);           // [N+1]
    int* CURSOR = ROWPTR + NN + 1;            // [N]
    int* BSUM   = CURSOR + NN;                // [NB]
    int* BOFF   = BSUM + NB;                  // [NB]
    int* CSRS   = BOFF + NB;                  // [E]
    unsigned short* R    = (unsigned short*)(CSRS + NE);
    unsigned short* Abf  = R;                          // [N,192] bf16 features
    unsigned short* W1hT = Abf + (size_t)NN * DD;      // [192,256]
    unsigned short* W1lT = W1hT + DIN * DD;
    unsigned short* W2hT = W1lT + DIN * DD;            // [192,192]
    unsigned short* W2lT = W2hT + DD * DD;
    unsigned short* WfhT = W2lT + DD * DD;             // [64,192]
    unsigned short* WflT = WfhT + DD * DF;

    const int edge_grid = (NE + 255) / 256;
    const int gemm_grid = (NN + 63) / 64;
    const int gat_grid  = (NN + 3) / 4;
    const int bns_grid  = (NN + 63) / 64;
    const int wsp_grid  = (W1G + W2G + WFG + 255) / 256;

    // ---- one memset: DEG + four BN stat vectors (contiguous) ----
    hipMemsetAsync(DEG, 0, (size_t)NN * 4 + 4 * DD * 4, stream);

    // ---- CSR build (once) ----
    hist_kernel<<<edge_grid, 256, 0, stream>>>(dst, DEG, NE);
    blocksum_kernel<<<NB, 256, 0, stream>>>(DEG, BSUM);
    scan_bsums<<<1, 256, 0, stream>>>(BSUM, BOFF, ROWPTR);
    expand_kernel<<<NB, 256, 0, stream>>>(DEG, BOFF, ROWPTR, CURSOR);
    scatter_kernel<<<edge_grid, 256, 0, stream>>>(src, dst, CURSOR, CSRS, NE);

    // ---- weight splits ----
    wsplit_all<<<wsp_grid, 256, 0, stream>>>(W1, W2, Wf, W1hT, W1lT, W2hT, W2lT, WfhT, WflT);

    // ================= layer 1 (dots fused) =================
    mfma_gemm<DIN, DD, 0, true><<<gemm_grid, 256, 0, stream>>>(
        x, nullptr,
        nullptr, nullptr, nullptr, nullptr, nullptr,
        nullptr, nullptr, nullptr, nullptr, nullptr,
        W1hT, W1lT, as1, ad1, AS4, AD4, nullptr, nullptr, Abf, NN);
    gat_gather<<<gat_grid, 256, 0, stream>>>(Abf, AS4, AD4, ROWPTR, CSRS, CB1);
    bn_stats<<<bns_grid, 192, 0, stream>>>(CB1, b1, S1a, S2a, NN);

    // ================= layer 2 (BN1 per-block + dots fused) =================
    mfma_gemm<DD, DD, 1, true><<<gemm_grid, 256, 0, stream>>>(
        CB1, nullptr,
        b1, S1a, S2a, g1, be1,
        nullptr, nullptr, nullptr, nullptr, nullptr,
        W2hT, W2lT, as2, ad2, AS4, AD4, nullptr, nullptr, Abf, NN);
    gat_gather<<<gat_grid, 256, 0, stream>>>(Abf, AS4, AD4, ROWPTR, CSRS, CB2);
    bn_stats<<<bns_grid, 192, 0, stream>>>(CB2, b2, S1b, S2b, NN);

    // ====== final: out = (bn1(h1) + bn2(h2)) @ Wf + bf (BN per-block in staging) ======
    mfma_gemm<DD, DF, 2, false><<<gemm_grid, 256, 0, stream>>>(
        CB1, CB2,
        b1, S1a, S2a, g1, be1,
        b2, S1b, S2b, g2, be2,
        WfhT, WflT, nullptr, nullptr, nullptr, nullptr, bf, out, nullptr, NN);
}

// Round 20
// 381.866 us; speedup vs baseline: 1.1062x; 1.0517x over previous
//
#include <hip/hip_runtime.h>

#define NN 50000
#define NE 800000
#define DIN 256
#define NH 3
#define HC 64
#define DD 192
#define DF 64
#define NB 196   // (NN + 255) / 256

typedef __attribute__((ext_vector_type(8))) short s8bf;            // 8 bf16 bit-patterns
typedef __attribute__((ext_vector_type(8))) unsigned short u16x8;
typedef __attribute__((ext_vector_type(4))) float f32x4;

// ---- fp32 -> bf16 helpers ----
__device__ __forceinline__ unsigned short f2bf(float f) {
    unsigned u = __float_as_uint(f);
    unsigned r = u + 0x7fffu + ((u >> 16) & 1u);   // round-to-nearest-even
    return (unsigned short)(r >> 16);
}
__device__ __forceinline__ float bf2f(unsigned short h) {
    return __uint_as_float(((unsigned)h) << 16);
}
__device__ __forceinline__ float rl_f(float v, int j) {
    return __int_as_float(__builtin_amdgcn_readlane(__float_as_int(v), j));
}

// ---- convert + transpose weights to bf16; thread = (k-octet, d) ----
#define W1G (DIN / 8 * DD)       // 6144 groups
#define W2G (DD / 8 * DD)        // 4608
#define WFG (DD / 8 * DF)        // 1536
__global__ __launch_bounds__(256)
void wsplit_all(const float* __restrict__ W1, const float* __restrict__ W2,
                const float* __restrict__ Wf,
                unsigned short* __restrict__ W1hT,
                unsigned short* __restrict__ W2hT,
                unsigned short* __restrict__ WfhT) {
    int idx = blockIdx.x * 256 + threadIdx.x;
    const float* W; unsigned short* Wh; int K, D, base;
    if (idx < W1G)                  { W = W1; Wh = W1hT; K = DIN; D = DD; base = idx; }
    else if (idx < W1G + W2G)       { W = W2; Wh = W2hT; K = DD;  D = DD; base = idx - W1G; }
    else if (idx < W1G + W2G + WFG) { W = Wf; Wh = WfhT; K = DD;  D = DF; base = idx - W1G - W2G; }
    else return;
    int kb = base / D, d = base - kb * D;   // consecutive threads -> consecutive d (coalesced reads)
    u16x8 hv;
#pragma unroll
    for (int q = 0; q < 8; ++q)
        hv[q] = f2bf(W[(size_t)(kb * 8 + q) * D + d]);
    *(u16x8*)(Wh + (size_t)d * K + kb * 8) = hv;
}

// ---- LDS full-K-panel bf16 MFMA GEMM; pipelined; bn_fin folded per-block ----
// MODE 0: A-source = A1 (fp32)                          -> Yb bf16
// MODE 1: A-source = bn1(relu(A1+bb1)); coefs per-BLOCK -> Yb bf16
// MODE 2: A-source = bn1(..A1..) + bn2(..A2..)          -> Yf fp32 + obias
// DOTS: epilogue computes per-row a_s/a_d -> as4o/ad4o
template<int K, int DOUT, int MODE, bool DOTS>
__global__ __launch_bounds__(256)
void mfma_gemm(const float* __restrict__ A1, const float* __restrict__ A2,
               const float* __restrict__ bb1, const float* __restrict__ S1a_,
               const float* __restrict__ S2a_, const float* __restrict__ g1_,
               const float* __restrict__ be1_,
               const float* __restrict__ bb2, const float* __restrict__ S1b_,
               const float* __restrict__ S2b_, const float* __restrict__ g2_,
               const float* __restrict__ be2_,
               const unsigned short* __restrict__ BhT,
               const float* __restrict__ att_s, const float* __restrict__ att_d,
               float4* __restrict__ as4o, float4* __restrict__ ad4o,
               const float* __restrict__ obias, float* __restrict__ Yf,
               unsigned short* __restrict__ Yb, int n) {
    constexpr int NT = DOUT / 64;            // 16-col tiles per wave (192->3, 64->1)
    constexpr int KB8 = K / 8;               // k-octets per row
    constexpr int NCF = (MODE == 2) ? 4 : (MODE == 1 ? 2 : 1);
    __shared__ unsigned short AH[64 * KB8 * 8];   // 32 KB (K=256) / 24 KB (K=192)
    __shared__ float sdots[DOTS ? 4 : 1][64][6];
    __shared__ float cf[NCF][DD];            // per-block BN scale/shift

    const int tid = threadIdx.x;
    const int wave = tid >> 6, lane = tid & 63;
    const int r = lane & 15, kg = lane >> 4;
    const int row0 = blockIdx.x * 64;
    const int col0 = wave * (DOUT / 4);

    // ---- per-block BN coefficient build (192 rsqrt once per block) ----
    if constexpr (MODE >= 1) {
        if (tid < DD) {
            const float invn = 1.0f / NN;
            float mu = S1a_[tid] * invn;
            float var = S2a_[tid] * invn - mu * mu;
            float sc = g1_[tid] * rsqrtf(var + 1e-5f);
            cf[0][tid] = sc;
            cf[1][tid] = be1_[tid] - mu * sc;
            if constexpr (MODE == 2) {
                mu = S1b_[tid] * invn;
                var = S2b_[tid] * invn - mu * mu;
                sc = g2_[tid] * rsqrtf(var + 1e-5f);
                cf[2][tid] = sc;
                cf[3][tid] = be2_[tid] - mu * sc;
            }
        }
        __syncthreads();
    }

    // ---- stage full A panel, 2-stage load pipeline ----
    constexpr int SIT = 64 * KB8 / 256;      // 8 (K=256) / 6 (K=192)
    auto aoff = [&](int i) {
        int idx = tid + i * 256;
        int row = idx / KB8, kb = idx - row * KB8;
        int grow = min(row0 + row, n - 1);
        return (size_t)grow * K + kb * 8;
    };
    float4 cv0, cv1, cu0, cu1;
    {
        size_t o0 = aoff(0);
        cv0 = *(const float4*)(A1 + o0);
        cv1 = *(const float4*)(A1 + o0 + 4);
        if constexpr (MODE == 2) {
            cu0 = *(const float4*)(A2 + o0);
            cu1 = *(const float4*)(A2 + o0 + 4);
        }
    }
#pragma unroll
    for (int i = 0; i < SIT; ++i) {
        float4 nv0, nv1, nu0, nu1;
        if (i + 1 < SIT) {
            size_t on = aoff(i + 1);
            nv0 = *(const float4*)(A1 + on);
            nv1 = *(const float4*)(A1 + on + 4);
            if constexpr (MODE == 2) {
                nu0 = *(const float4*)(A2 + on);
                nu1 = *(const float4*)(A2 + on + 4);
            }
        }
        int idx = tid + i * 256;
        int row = idx / KB8, kb = idx - row * KB8;
        int j = kb * 8;
        float v[8];
        *(float4*)&v[0] = cv0; *(float4*)&v[4] = cv1;
        if constexpr (MODE >= 1) {
#pragma unroll
            for (int q = 0; q < 8; ++q)
                v[q] = fmaxf(v[q] + bb1[j + q], 0.f) * cf[0][j + q] + cf[1][j + q];
        }
        if constexpr (MODE == 2) {
            float u[8];
            *(float4*)&u[0] = cu0; *(float4*)&u[4] = cu1;
#pragma unroll
            for (int q = 0; q < 8; ++q)
                v[q] += fmaxf(u[q] + bb2[j + q], 0.f) * cf[2][j + q] + cf[3][j + q];
        }
        u16x8 hv;
#pragma unroll
        for (int q = 0; q < 8; ++q)
            hv[q] = f2bf(v[q]);
        int sw = kb ^ (row & 7);
        *(u16x8*)&AH[(row * KB8 + sw) * 8] = hv;
        cv0 = nv0; cv1 = nv1;
        if constexpr (MODE == 2) { cu0 = nu0; cu1 = nu1; }
    }
    __syncthreads();                          // the only staging barrier

    int boff[NT];
#pragma unroll
    for (int t = 0; t < NT; ++t)
        boff[t] = (col0 + t * 16 + r) * K + kg * 8;

    f32x4 acc[4][NT] = {};

    auto loadB = [&](int k0, s8bf* bh) {
#pragma unroll
        for (int t = 0; t < NT; ++t)
            bh[t] = *(const s8bf*)(BhT + boff[t] + k0);
    };
    auto loadA = [&](int k0, s8bf* ah) {
        const int kb = k0 / 8 + kg;
#pragma unroll
        for (int g = 0; g < 4; ++g) {
            int row = g * 16 + r;
            int sw = kb ^ (row & 7);
            ah[g] = *(const s8bf*)&AH[(row * KB8 + sw) * 8];
        }
    };

    // ---- K loop, software-pipelined: prefetch (B global, A LDS) over MFMAs ----
    s8bf bh[NT], ah4[4];
    loadB(0, bh);
    loadA(0, ah4);
#pragma unroll
    for (int k0 = 0; k0 < K; k0 += 32) {
        s8bf nbh[NT], nah[4];
        if (k0 + 32 < K) {
            loadB(k0 + 32, nbh);
            loadA(k0 + 32, nah);
        }
#pragma unroll
        for (int g = 0; g < 4; ++g)
#pragma unroll
            for (int t = 0; t < NT; ++t)
                acc[g][t] = __builtin_amdgcn_mfma_f32_16x16x32_bf16(ah4[g], bh[t], acc[g][t], 0, 0, 0);
#pragma unroll
        for (int t = 0; t < NT; ++t) bh[t] = nbh[t];
#pragma unroll
        for (int g = 0; g < 4; ++g) ah4[g] = nah[g];
    }

    // ---- C write. layout: col = lane&15 (within tile), row = (lane>>4)*4 + reg ----
#pragma unroll
    for (int t = 0; t < NT; ++t) {
        int col = col0 + t * 16 + r;
        float b = (MODE == 2) ? obias[col] : 0.f;
#pragma unroll
        for (int g = 0; g < 4; ++g) {
#pragma unroll
            for (int rr = 0; rr < 4; ++rr) {
                int row = row0 + g * 16 + kg * 4 + rr;
                if (row < n) {
                    if constexpr (MODE == 2)
                        Yf[(size_t)row * DOUT + col] = acc[g][t][rr] + b;
                    else
                        Yb[(size_t)row * DOUT + col] = f2bf(acc[g][t][rr]);
                }
            }
        }
    }

    // ---- fused attention dots epilogue ----
    if constexpr (DOTS) {
        float asv[NT], adv[NT];
        int headt[NT];
#pragma unroll
        for (int t = 0; t < NT; ++t) {
            int col = col0 + t * 16 + r;
            asv[t] = att_s[col];
            adv[t] = att_d[col];
            headt[t] = (col0 + t * 16) >> 6;   // wave-uniform
        }
#pragma unroll
        for (int g = 0; g < 4; ++g) {
#pragma unroll
            for (int rr = 0; rr < 4; ++rr) {
                float rs0 = 0.f, rs1 = 0.f, rs2 = 0.f;
                float rd0 = 0.f, rd1 = 0.f, rd2 = 0.f;
#pragma unroll
                for (int t = 0; t < NT; ++t) {
                    float v = acc[g][t][rr];
                    float s = v * asv[t], dd = v * adv[t];
                    if (headt[t] == 0)      { rs0 += s; rd0 += dd; }
                    else if (headt[t] == 1) { rs1 += s; rd1 += dd; }
                    else                    { rs2 += s; rd2 += dd; }
                }
#pragma unroll
                for (int m = 1; m < 16; m <<= 1) {
                    rs0 += __shfl_xor(rs0, m); rs1 += __shfl_xor(rs1, m); rs2 += __shfl_xor(rs2, m);
                    rd0 += __shfl_xor(rd0, m); rd1 += __shfl_xor(rd1, m); rd2 += __shfl_xor(rd2, m);
                }
                if (r == 0) {
                    int row = g * 16 + kg * 4 + rr;
                    sdots[wave][row][0] = rs0; sdots[wave][row][1] = rs1; sdots[wave][row][2] = rs2;
                    sdots[wave][row][3] = rd0; sdots[wave][row][4] = rd1; sdots[wave][row][5] = rd2;
                }
            }
        }
        __syncthreads();
        if (tid < 64) {
            int row = row0 + tid;
            if (row < n) {
                float s0 = 0.f, s1 = 0.f, s2 = 0.f, d0 = 0.f, d1 = 0.f, d2 = 0.f;
#pragma unroll
                for (int w = 0; w < 4; ++w) {
                    s0 += sdots[w][tid][0]; s1 += sdots[w][tid][1]; s2 += sdots[w][tid][2];
                    d0 += sdots[w][tid][3]; d1 += sdots[w][tid][4]; d2 += sdots[w][tid][5];
                }
                as4o[row] = make_float4(s0, s1, s2, 0.f);
                ad4o[row] = make_float4(d0, d1, d2, 0.f);
            }
        }
    }
}

// ============ CSR build ============
__global__ void hist_kernel(const int* __restrict__ dst, int* __restrict__ deg, int ne) {
    int e = blockIdx.x * blockDim.x + threadIdx.x;
    if (e < ne) atomicAdd(&deg[dst[e]], 1);
}

__global__ __launch_bounds__(256)
void blocksum_kernel(const int* __restrict__ deg, int* __restrict__ bsum) {
    int i = blockIdx.x * 256 + threadIdx.x;
    int v = (i < NN) ? deg[i] : 0;
#pragma unroll
    for (int off = 32; off; off >>= 1) v += __shfl_down(v, off);
    __shared__ int ws[4];
    if ((threadIdx.x & 63) == 0) ws[threadIdx.x >> 6] = v;
    __syncthreads();
    if (threadIdx.x == 0) bsum[blockIdx.x] = ws[0] + ws[1] + ws[2] + ws[3];
}

__global__ __launch_bounds__(256)
void scan_bsums(const int* __restrict__ bsum, int* __restrict__ boff,
                int* __restrict__ rowptr) {
    __shared__ int s[256];
    int t = threadIdx.x;
    int v = (t < NB) ? bsum[t] : 0;
    s[t] = v;
    __syncthreads();
    for (int off = 1; off < 256; off <<= 1) {
        int u = (t >= off) ? s[t - off] : 0;
        __syncthreads();
        s[t] += u;
        __syncthreads();
    }
    if (t < NB) boff[t] = s[t] - v;
    if (t == 255) rowptr[NN] = s[255];
}

__global__ __launch_bounds__(256)
void expand_kernel(const int* __restrict__ deg, const int* __restrict__ boff,
                   int* __restrict__ rowptr, int* __restrict__ cursor) {
    __shared__ int s[256];
    int t = threadIdx.x;
    int i = blockIdx.x * 256 + t;
    int v = (i < NN) ? deg[i] : 0;
    s[t] = v;
    __syncthreads();
    for (int off = 1; off < 256; off <<= 1) {
        int u = (t >= off) ? s[t - off] : 0;
        __syncthreads();
        s[t] += u;
        __syncthreads();
    }
    if (i < NN) {
        int excl = s[t] - v + boff[blockIdx.x];
        rowptr[i] = excl;
        cursor[i] = excl;
    }
}

__global__ void scatter_kernel(const int* __restrict__ src, const int* __restrict__ dst,
                               int* __restrict__ cursor, int* __restrict__ csr_src, int ne) {
    int e = blockIdx.x * blockDim.x + threadIdx.x;
    if (e >= ne) return;
    int d = dst[e];
    int pos = atomicAdd(&cursor[d], 1);
    csr_src[pos] = src[e];
}

// ============ GAT gather: 8-edge batched loads for HBM-latency hiding ============
__global__ __launch_bounds__(256)
void gat_gather(const unsigned short* __restrict__ xf,
                const float4* __restrict__ as4, const float4* __restrict__ ad4,
                const int* __restrict__ rowptr, const int* __restrict__ csr_src,
                float* __restrict__ outp) {
    int d = blockIdx.x * 4 + (threadIdx.x >> 6);
    if (d >= NN) return;
    const int lane = threadIdx.x & 63;
    const int beg = rowptr[d], end = rowptr[d + 1];
    const float4 adv = ad4[d];

    float a0 = 0.f, a1 = 0.f, a2 = 0.f;
    float den0 = 0.f, den1 = 0.f, den2 = 0.f;

    for (int base = beg; base < end; base += 64) {
        const int nb = min(64, end - base);
        int sl = 0;
        float w0 = 0.f, w1 = 0.f, w2 = 0.f;
        if (lane < nb) {
            sl = csr_src[base + lane];
            float4 av = as4[sl];               // one 16B gather per lane
            float e0 = av.x + adv.x;
            float e1 = av.y + adv.y;
            float e2 = av.z + adv.z;
            e0 = e0 > 0.f ? e0 : 0.2f * e0;
            e1 = e1 > 0.f ? e1 : 0.2f * e1;
            e2 = e2 > 0.f ? e2 : 0.2f * e2;
            w0 = __expf(e0); w1 = __expf(e1); w2 = __expf(e2);
        }
        float r0 = w0, r1 = w1, r2 = w2;
#pragma unroll
        for (int off = 1; off < 64; off <<= 1) {
            r0 += __shfl_xor(r0, off);
            r1 += __shfl_xor(r1, off);
            r2 += __shfl_xor(r2, off);
        }
        den0 += r0; den1 += r1; den2 += r2;

        int j = 0;
        for (; j + 8 <= nb; j += 8) {
            const unsigned short* xp[8];
            float uw0[8], uw1[8], uw2[8];
#pragma unroll
            for (int k = 0; k < 8; ++k) {
                int s = __builtin_amdgcn_readlane(sl, j + k);
                xp[k] = xf + (size_t)s * DD;
                uw0[k] = rl_f(w0, j + k);
                uw1[k] = rl_f(w1, j + k);
                uw2[k] = rl_f(w2, j + k);
            }
            unsigned short f0[8], f1[8], f2[8];
#pragma unroll
            for (int k = 0; k < 8; ++k) {
                f0[k] = xp[k][lane];
                f1[k] = xp[k][64 + lane];
                f2[k] = xp[k][128 + lane];
            }
#pragma unroll
            for (int k = 0; k < 8; ++k) {
                a0 = fmaf(bf2f(f0[k]), uw0[k], a0);
                a1 = fmaf(bf2f(f1[k]), uw1[k], a1);
                a2 = fmaf(bf2f(f2[k]), uw2[k], a2);
            }
        }
        for (; j < nb; ++j) {
            int s = __builtin_amdgcn_readlane(sl, j);
            float u0 = rl_f(w0, j), u1 = rl_f(w1, j), u2 = rl_f(w2, j);
            const unsigned short* xp = xf + (size_t)s * DD;
            a0 = fmaf(bf2f(xp[lane]),       u0, a0);
            a1 = fmaf(bf2f(xp[64 + lane]),  u1, a1);
            a2 = fmaf(bf2f(xp[128 + lane]), u2, a2);
        }
    }
    size_t o = (size_t)d * DD + lane;
    outp[o]       = a0 / (den0 + 1e-16f);
    outp[o + 64]  = a1 / (den1 + 1e-16f);
    outp[o + 128] = a2 / (den2 + 1e-16f);
}

// ---- BN pass 1: 64 rows/block (782 blocks) for latency hiding ----
__global__ __launch_bounds__(192)
void bn_stats(const float* __restrict__ hbuf, const float* __restrict__ bias,
              float* __restrict__ s1, float* __restrict__ s2, int n) {
    int j = threadIdx.x;
    float b = bias[j];
    int r0 = blockIdx.x * 64;
    int r1 = min(r0 + 64, n);
    float a = 0.f, q = 0.f;
    for (int r = r0; r < r1; ++r) {
        float v = hbuf[(size_t)r * DD + j] + b;
        v = fmaxf(v, 0.f);
        a += v; q += v * v;
    }
    atomicAdd(&s1[j], a);
    atomicAdd(&s2[j], q);
}

extern "C" void kernel_launch(void* const* d_in, const int* in_sizes, int n_in,
                              void* d_out, int out_size, void* d_ws, size_t ws_size,
                              hipStream_t stream) {
    const float* x   = (const float*)d_in[0];
    const float* W1  = (const float*)d_in[1];
    const float* as1 = (const float*)d_in[2];
    const float* ad1 = (const float*)d_in[3];
    const float* b1  = (const float*)d_in[4];
    const float* g1  = (const float*)d_in[5];
    const float* be1 = (const float*)d_in[6];
    const float* W2  = (const float*)d_in[7];
    const float* as2 = (const float*)d_in[8];
    const float* ad2 = (const float*)d_in[9];
    const float* b2  = (const float*)d_in[10];
    const float* g2  = (const float*)d_in[11];
    const float* be2 = (const float*)d_in[12];
    const float* Wf  = (const float*)d_in[13];
    const float* bf  = (const float*)d_in[14];
    const int*   ei  = (const int*)d_in[15];
    const int* src = ei;
    const int* dst = ei + NE;
    float* out = (float*)d_out;

    float* ws = (float*)d_ws;
    float* CB1 = ws;                          // [N,192]
    float* CB2 = CB1 + (size_t)NN * DD;       // [N,192]
    float4* AS4 = (float4*)(CB2 + (size_t)NN * DD);   // [N] float4
    float4* AD4 = AS4 + NN;                   // [N] float4
    int* DEG   = (int*)(AD4 + NN);            // [N]  (zeroed together with stats)
    float* S1a = (float*)(DEG + NN);          // [192] x4 stats
    float* S2a = S1a + DD;
    float* S1b = S2a + DD;
    float* S2b = S1b + DD;
    int* ROWPTR = (int*)(S2b + DD);           // [N+1]
    int* CURSOR = ROWPTR + NN + 1;            // [N]
    int* BSUM   = CURSOR + NN;                // [NB]
    int* BOFF   = BSUM + NB;                  // [NB]
    int* CSRS   = BOFF + NB;                  // [E]
    unsigned short* R    = (unsigned short*)(CSRS + NE);
    unsigned short* Abf  = R;                          // [N,192] bf16 features
    unsigned short* W1hT = Abf + (size_t)NN * DD;      // [192,256]
    unsigned short* W2hT = W1hT + DIN * DD;            // [192,192]
    unsigned short* WfhT = W2hT + DD * DD;             // [64,192]

    const int edge_grid = (NE + 255) / 256;
    const int gemm_grid = (NN + 63) / 64;
    const int gat_grid  = (NN + 3) / 4;
    const int bns_grid  = (NN + 63) / 64;
    const int wsp_grid  = (W1G + W2G + WFG + 255) / 256;

    // ---- one memset: DEG + four BN stat vectors (contiguous) ----
    hipMemsetAsync(DEG, 0, (size_t)NN * 4 + 4 * DD * 4, stream);

    // ---- CSR build (once) ----
    hist_kernel<<<edge_grid, 256, 0, stream>>>(dst, DEG, NE);
    blocksum_kernel<<<NB, 256, 0, stream>>>(DEG, BSUM);
    scan_bsums<<<1, 256, 0, stream>>>(BSUM, BOFF, ROWPTR);
    expand_kernel<<<NB, 256, 0, stream>>>(DEG, BOFF, ROWPTR, CURSOR);
    scatter_kernel<<<edge_grid, 256, 0, stream>>>(src, dst, CURSOR, CSRS, NE);

    // ---- weight conversion ----
    wsplit_all<<<wsp_grid, 256, 0, stream>>>(W1, W2, Wf, W1hT, W2hT, WfhT);

    // ================= layer 1 (dots fused) =================
    mfma_gemm<DIN, DD, 0, true><<<gemm_grid, 256, 0, stream>>>(
        x, nullptr,
        nullptr, nullptr, nullptr, nullptr, nullptr,
        nullptr, nullptr, nullptr, nullptr, nullptr,
        W1hT, as1, ad1, AS4, AD4, nullptr, nullptr, Abf, NN);
    gat_gather<<<gat_grid, 256, 0, stream>>>(Abf, AS4, AD4, ROWPTR, CSRS, CB1);
    bn_stats<<<bns_grid, 192, 0, stream>>>(CB1, b1, S1a, S2a, NN);

    // ================= layer 2 (BN1 per-block + dots fused) =================
    mfma_gemm<DD, DD, 1, true><<<gemm_grid, 256, 0, stream>>>(
        CB1, nullptr,
        b1, S1a, S2a, g1, be1,
        nullptr, nullptr, nullptr, nullptr, nullptr,
        W2hT, as2, ad2, AS4, AD4, nullptr, nullptr, Abf, NN);
    gat_gather<<<gat_grid, 256, 0, stream>>>(Abf, AS4, AD4, ROWPTR, CSRS, CB2);
    bn_stats<<<bns_grid, 192, 0, stream>>>(CB2, b2, S1b, S2b, NN);

    // ====== final: out = (bn1(h1) + bn2(h2)) @ Wf + bf (BN per-block in staging) ======
    mfma_gemm<DD, DF, 2, false><<<gemm_grid, 256, 0, stream>>>(
        CB1, CB2,
        b1, S1a, S2a, g1, be1,
        b2, S1b, S2b, g2, be2,
        WfhT, nullptr, nullptr, nullptr, nullptr, bf, out, nullptr, NN);
}

// Round 21
// 334.598 us; speedup vs baseline: 1.2625x; 1.1413x over previous
//
#include <hip/hip_runtime.h>

#define NN 50000
#define NE 800000
#define DIN 256
#define NH 3
#define HC 64
#define DD 192
#define DF 64
#define NB 196   // (NN + 255) / 256
#define NSLOT 64 // hierarchical BN-stat slots

typedef __attribute__((ext_vector_type(8))) short s8bf;            // 8 bf16 bit-patterns
typedef __attribute__((ext_vector_type(8))) unsigned short u16x8;
typedef __attribute__((ext_vector_type(4))) float f32x4;

// ---- fp32 -> bf16 helpers ----
__device__ __forceinline__ unsigned short f2bf(float f) {
    unsigned u = __float_as_uint(f);
    unsigned r = u + 0x7fffu + ((u >> 16) & 1u);   // round-to-nearest-even
    return (unsigned short)(r >> 16);
}
__device__ __forceinline__ float bf2f(unsigned short h) {
    return __uint_as_float(((unsigned)h) << 16);
}
__device__ __forceinline__ float rl_f(float v, int j) {
    return __int_as_float(__builtin_amdgcn_readlane(__float_as_int(v), j));
}

// ---- convert + transpose weights to bf16; thread = (k-octet, d) ----
#define W1G (DIN / 8 * DD)       // 6144 groups
#define W2G (DD / 8 * DD)        // 4608
#define WFG (DD / 8 * DF)        // 1536
__global__ __launch_bounds__(256)
void wsplit_all(const float* __restrict__ W1, const float* __restrict__ W2,
                const float* __restrict__ Wf,
                unsigned short* __restrict__ W1hT,
                unsigned short* __restrict__ W2hT,
                unsigned short* __restrict__ WfhT) {
    int idx = blockIdx.x * 256 + threadIdx.x;
    const float* W; unsigned short* Wh; int K, D, base;
    if (idx < W1G)                  { W = W1; Wh = W1hT; K = DIN; D = DD; base = idx; }
    else if (idx < W1G + W2G)       { W = W2; Wh = W2hT; K = DD;  D = DD; base = idx - W1G; }
    else if (idx < W1G + W2G + WFG) { W = Wf; Wh = WfhT; K = DD;  D = DF; base = idx - W1G - W2G; }
    else return;
    int kb = base / D, d = base - kb * D;   // consecutive threads -> consecutive d (coalesced reads)
    u16x8 hv;
#pragma unroll
    for (int q = 0; q < 8; ++q)
        hv[q] = f2bf(W[(size_t)(kb * 8 + q) * D + d]);
    *(u16x8*)(Wh + (size_t)d * K + kb * 8) = hv;
}

// ---- LDS full-K-panel bf16 MFMA GEMM; pipelined; bn_fin folded per-block ----
// MODE 0: A-source = A1 (fp32)                          -> Yb bf16
// MODE 1: A-source = bn1(relu(A1+bb1)); coefs per-BLOCK -> Yb bf16
// MODE 2: A-source = bn1(..A1..) + bn2(..A2..)          -> Yf fp32 + obias
// DOTS: epilogue computes per-row a_s/a_d -> as4o/ad4o
template<int K, int DOUT, int MODE, bool DOTS>
__global__ __launch_bounds__(256)
void mfma_gemm(const float* __restrict__ A1, const float* __restrict__ A2,
               const float* __restrict__ bb1, const float* __restrict__ S1a_,
               const float* __restrict__ S2a_, const float* __restrict__ g1_,
               const float* __restrict__ be1_,
               const float* __restrict__ bb2, const float* __restrict__ S1b_,
               const float* __restrict__ S2b_, const float* __restrict__ g2_,
               const float* __restrict__ be2_,
               const unsigned short* __restrict__ BhT,
               const float* __restrict__ att_s, const float* __restrict__ att_d,
               float4* __restrict__ as4o, float4* __restrict__ ad4o,
               const float* __restrict__ obias, float* __restrict__ Yf,
               unsigned short* __restrict__ Yb, int n) {
    constexpr int NT = DOUT / 64;            // 16-col tiles per wave (192->3, 64->1)
    constexpr int KB8 = K / 8;               // k-octets per row
    constexpr int NCF = (MODE == 2) ? 4 : (MODE == 1 ? 2 : 1);
    __shared__ unsigned short AH[64 * KB8 * 8];   // 32 KB (K=256) / 24 KB (K=192)
    __shared__ float sdots[DOTS ? 4 : 1][64][6];
    __shared__ float cf[NCF][DD];            // per-block BN scale/shift

    const int tid = threadIdx.x;
    const int wave = tid >> 6, lane = tid & 63;
    const int r = lane & 15, kg = lane >> 4;
    const int row0 = blockIdx.x * 64;
    const int col0 = wave * (DOUT / 4);

    // ---- per-block BN coefficient build (192 rsqrt once per block) ----
    if constexpr (MODE >= 1) {
        if (tid < DD) {
            const float invn = 1.0f / NN;
            float mu = S1a_[tid] * invn;
            float var = S2a_[tid] * invn - mu * mu;
            float sc = g1_[tid] * rsqrtf(var + 1e-5f);
            cf[0][tid] = sc;
            cf[1][tid] = be1_[tid] - mu * sc;
            if constexpr (MODE == 2) {
                mu = S1b_[tid] * invn;
                var = S2b_[tid] * invn - mu * mu;
                sc = g2_[tid] * rsqrtf(var + 1e-5f);
                cf[2][tid] = sc;
                cf[3][tid] = be2_[tid] - mu * sc;
            }
        }
        __syncthreads();
    }

    // ---- stage full A panel, 2-stage load pipeline ----
    constexpr int SIT = 64 * KB8 / 256;      // 8 (K=256) / 6 (K=192)
    auto aoff = [&](int i) {
        int idx = tid + i * 256;
        int row = idx / KB8, kb = idx - row * KB8;
        int grow = min(row0 + row, n - 1);
        return (size_t)grow * K + kb * 8;
    };
    float4 cv0, cv1, cu0, cu1;
    {
        size_t o0 = aoff(0);
        cv0 = *(const float4*)(A1 + o0);
        cv1 = *(const float4*)(A1 + o0 + 4);
        if constexpr (MODE == 2) {
            cu0 = *(const float4*)(A2 + o0);
            cu1 = *(const float4*)(A2 + o0 + 4);
        }
    }
#pragma unroll
    for (int i = 0; i < SIT; ++i) {
        float4 nv0, nv1, nu0, nu1;
        if (i + 1 < SIT) {
            size_t on = aoff(i + 1);
            nv0 = *(const float4*)(A1 + on);
            nv1 = *(const float4*)(A1 + on + 4);
            if constexpr (MODE == 2) {
                nu0 = *(const float4*)(A2 + on);
                nu1 = *(const float4*)(A2 + on + 4);
            }
        }
        int idx = tid + i * 256;
        int row = idx / KB8, kb = idx - row * KB8;
        int j = kb * 8;
        float v[8];
        *(float4*)&v[0] = cv0; *(float4*)&v[4] = cv1;
        if constexpr (MODE >= 1) {
#pragma unroll
            for (int q = 0; q < 8; ++q)
                v[q] = fmaxf(v[q] + bb1[j + q], 0.f) * cf[0][j + q] + cf[1][j + q];
        }
        if constexpr (MODE == 2) {
            float u[8];
            *(float4*)&u[0] = cu0; *(float4*)&u[4] = cu1;
#pragma unroll
            for (int q = 0; q < 8; ++q)
                v[q] += fmaxf(u[q] + bb2[j + q], 0.f) * cf[2][j + q] + cf[3][j + q];
        }
        u16x8 hv;
#pragma unroll
        for (int q = 0; q < 8; ++q)
            hv[q] = f2bf(v[q]);
        int sw = kb ^ (row & 7);
        *(u16x8*)&AH[(row * KB8 + sw) * 8] = hv;
        cv0 = nv0; cv1 = nv1;
        if constexpr (MODE == 2) { cu0 = nu0; cu1 = nu1; }
    }
    __syncthreads();                          // the only staging barrier

    int boff[NT];
#pragma unroll
    for (int t = 0; t < NT; ++t)
        boff[t] = (col0 + t * 16 + r) * K + kg * 8;

    f32x4 acc[4][NT] = {};

    auto loadB = [&](int k0, s8bf* bh) {
#pragma unroll
        for (int t = 0; t < NT; ++t)
            bh[t] = *(const s8bf*)(BhT + boff[t] + k0);
    };
    auto loadA = [&](int k0, s8bf* ah) {
        const int kb = k0 / 8 + kg;
#pragma unroll
        for (int g = 0; g < 4; ++g) {
            int row = g * 16 + r;
            int sw = kb ^ (row & 7);
            ah[g] = *(const s8bf*)&AH[(row * KB8 + sw) * 8];
        }
    };

    // ---- K loop, software-pipelined: prefetch (B global, A LDS) over MFMAs ----
    s8bf bh[NT], ah4[4];
    loadB(0, bh);
    loadA(0, ah4);
#pragma unroll
    for (int k0 = 0; k0 < K; k0 += 32) {
        s8bf nbh[NT], nah[4];
        if (k0 + 32 < K) {
            loadB(k0 + 32, nbh);
            loadA(k0 + 32, nah);
        }
#pragma unroll
        for (int g = 0; g < 4; ++g)
#pragma unroll
            for (int t = 0; t < NT; ++t)
                acc[g][t] = __builtin_amdgcn_mfma_f32_16x16x32_bf16(ah4[g], bh[t], acc[g][t], 0, 0, 0);
#pragma unroll
        for (int t = 0; t < NT; ++t) bh[t] = nbh[t];
#pragma unroll
        for (int g = 0; g < 4; ++g) ah4[g] = nah[g];
    }

    // ---- C write. layout: col = lane&15 (within tile), row = (lane>>4)*4 + reg ----
#pragma unroll
    for (int t = 0; t < NT; ++t) {
        int col = col0 + t * 16 + r;
        float b = (MODE == 2) ? obias[col] : 0.f;
#pragma unroll
        for (int g = 0; g < 4; ++g) {
#pragma unroll
            for (int rr = 0; rr < 4; ++rr) {
                int row = row0 + g * 16 + kg * 4 + rr;
                if (row < n) {
                    if constexpr (MODE == 2)
                        Yf[(size_t)row * DOUT + col] = acc[g][t][rr] + b;
                    else
                        Yb[(size_t)row * DOUT + col] = f2bf(acc[g][t][rr]);
                }
            }
        }
    }

    // ---- fused attention dots epilogue ----
    if constexpr (DOTS) {
        float asv[NT], adv[NT];
        int headt[NT];
#pragma unroll
        for (int t = 0; t < NT; ++t) {
            int col = col0 + t * 16 + r;
            asv[t] = att_s[col];
            adv[t] = att_d[col];
            headt[t] = (col0 + t * 16) >> 6;   // wave-uniform
        }
#pragma unroll
        for (int g = 0; g < 4; ++g) {
#pragma unroll
            for (int rr = 0; rr < 4; ++rr) {
                float rs0 = 0.f, rs1 = 0.f, rs2 = 0.f;
                float rd0 = 0.f, rd1 = 0.f, rd2 = 0.f;
#pragma unroll
                for (int t = 0; t < NT; ++t) {
                    float v = acc[g][t][rr];
                    float s = v * asv[t], dd = v * adv[t];
                    if (headt[t] == 0)      { rs0 += s; rd0 += dd; }
                    else if (headt[t] == 1) { rs1 += s; rd1 += dd; }
                    else                    { rs2 += s; rd2 += dd; }
                }
#pragma unroll
                for (int m = 1; m < 16; m <<= 1) {
                    rs0 += __shfl_xor(rs0, m); rs1 += __shfl_xor(rs1, m); rs2 += __shfl_xor(rs2, m);
                    rd0 += __shfl_xor(rd0, m); rd1 += __shfl_xor(rd1, m); rd2 += __shfl_xor(rd2, m);
                }
                if (r == 0) {
                    int row = g * 16 + kg * 4 + rr;
                    sdots[wave][row][0] = rs0; sdots[wave][row][1] = rs1; sdots[wave][row][2] = rs2;
                    sdots[wave][row][3] = rd0; sdots[wave][row][4] = rd1; sdots[wave][row][5] = rd2;
                }
            }
        }
        __syncthreads();
        if (tid < 64) {
            int row = row0 + tid;
            if (row < n) {
                float s0 = 0.f, s1 = 0.f, s2 = 0.f, d0 = 0.f, d1 = 0.f, d2 = 0.f;
#pragma unroll
                for (int w = 0; w < 4; ++w) {
                    s0 += sdots[w][tid][0]; s1 += sdots[w][tid][1]; s2 += sdots[w][tid][2];
                    d0 += sdots[w][tid][3]; d1 += sdots[w][tid][4]; d2 += sdots[w][tid][5];
                }
                as4o[row] = make_float4(s0, s1, s2, 0.f);
                ad4o[row] = make_float4(d0, d1, d2, 0.f);
            }
        }
    }
}

// ============ CSR build ============
__global__ void hist_kernel(const int* __restrict__ dst, int* __restrict__ deg, int ne) {
    int e = blockIdx.x * blockDim.x + threadIdx.x;
    if (e < ne) atomicAdd(&deg[dst[e]], 1);
}

__global__ __launch_bounds__(256)
void blocksum_kernel(const int* __restrict__ deg, int* __restrict__ bsum) {
    int i = blockIdx.x * 256 + threadIdx.x;
    int v = (i < NN) ? deg[i] : 0;
#pragma unroll
    for (int off = 32; off; off >>= 1) v += __shfl_down(v, off);
    __shared__ int ws[4];
    if ((threadIdx.x & 63) == 0) ws[threadIdx.x >> 6] = v;
    __syncthreads();
    if (threadIdx.x == 0) bsum[blockIdx.x] = ws[0] + ws[1] + ws[2] + ws[3];
}

__global__ __launch_bounds__(256)
void scan_bsums(const int* __restrict__ bsum, int* __restrict__ boff,
                int* __restrict__ rowptr) {
    __shared__ int s[256];
    int t = threadIdx.x;
    int v = (t < NB) ? bsum[t] : 0;
    s[t] = v;
    __syncthreads();
    for (int off = 1; off < 256; off <<= 1) {
        int u = (t >= off) ? s[t - off] : 0;
        __syncthreads();
        s[t] += u;
        __syncthreads();
    }
    if (t < NB) boff[t] = s[t] - v;
    if (t == 255) rowptr[NN] = s[255];
}

__global__ __launch_bounds__(256)
void expand_kernel(const int* __restrict__ deg, const int* __restrict__ boff,
                   int* __restrict__ rowptr, int* __restrict__ cursor) {
    __shared__ int s[256];
    int t = threadIdx.x;
    int i = blockIdx.x * 256 + t;
    int v = (i < NN) ? deg[i] : 0;
    s[t] = v;
    __syncthreads();
    for (int off = 1; off < 256; off <<= 1) {
        int u = (t >= off) ? s[t - off] : 0;
        __syncthreads();
        s[t] += u;
        __syncthreads();
    }
    if (i < NN) {
        int excl = s[t] - v + boff[blockIdx.x];
        rowptr[i] = excl;
        cursor[i] = excl;
    }
}

__global__ void scatter_kernel(const int* __restrict__ src, const int* __restrict__ dst,
                               int* __restrict__ cursor, int* __restrict__ csr_src, int ne) {
    int e = blockIdx.x * blockDim.x + threadIdx.x;
    if (e >= ne) return;
    int d = dst[e];
    int pos = atomicAdd(&cursor[d], 1);
    csr_src[pos] = src[e];
}

// ============ GAT gather + hierarchical BN stats (64 slots) ============
// 8-edge batched loads; block LDS reduce -> 384 atomics into slot blockIdx&63.
// Grid is exactly NN/4 blocks (NN % 4 == 0): no early returns, barrier-safe.
__global__ __launch_bounds__(256)
void gat_gather(const unsigned short* __restrict__ xf,
                const float4* __restrict__ as4, const float4* __restrict__ ad4,
                const int* __restrict__ rowptr, const int* __restrict__ csr_src,
                const float* __restrict__ bias, float* __restrict__ sb1,
                float* __restrict__ sb2, float* __restrict__ outp) {
    __shared__ float bs1[4][DD];
    __shared__ float bs2[4][DD];
    const int wid = threadIdx.x >> 6;
    const int lane = threadIdx.x & 63;
    const int d = blockIdx.x * 4 + wid;
    const int beg = rowptr[d], end = rowptr[d + 1];
    const float4 adv = ad4[d];

    float a0 = 0.f, a1 = 0.f, a2 = 0.f;
    float den0 = 0.f, den1 = 0.f, den2 = 0.f;

    for (int base = beg; base < end; base += 64) {
        const int nb = min(64, end - base);
        int sl = 0;
        float w0 = 0.f, w1 = 0.f, w2 = 0.f;
        if (lane < nb) {
            sl = csr_src[base + lane];
            float4 av = as4[sl];               // one 16B gather per lane
            float e0 = av.x + adv.x;
            float e1 = av.y + adv.y;
            float e2 = av.z + adv.z;
            e0 = e0 > 0.f ? e0 : 0.2f * e0;
            e1 = e1 > 0.f ? e1 : 0.2f * e1;
            e2 = e2 > 0.f ? e2 : 0.2f * e2;
            w0 = __expf(e0); w1 = __expf(e1); w2 = __expf(e2);
        }
        float r0 = w0, r1 = w1, r2 = w2;
#pragma unroll
        for (int off = 1; off < 64; off <<= 1) {
            r0 += __shfl_xor(r0, off);
            r1 += __shfl_xor(r1, off);
            r2 += __shfl_xor(r2, off);
        }
        den0 += r0; den1 += r1; den2 += r2;

        int j = 0;
        for (; j + 8 <= nb; j += 8) {
            const unsigned short* xp[8];
            float uw0[8], uw1[8], uw2[8];
#pragma unroll
            for (int k = 0; k < 8; ++k) {
                int s = __builtin_amdgcn_readlane(sl, j + k);
                xp[k] = xf + (size_t)s * DD;
                uw0[k] = rl_f(w0, j + k);
                uw1[k] = rl_f(w1, j + k);
                uw2[k] = rl_f(w2, j + k);
            }
            unsigned short f0[8], f1[8], f2[8];
#pragma unroll
            for (int k = 0; k < 8; ++k) {
                f0[k] = xp[k][lane];
                f1[k] = xp[k][64 + lane];
                f2[k] = xp[k][128 + lane];
            }
#pragma unroll
            for (int k = 0; k < 8; ++k) {
                a0 = fmaf(bf2f(f0[k]), uw0[k], a0);
                a1 = fmaf(bf2f(f1[k]), uw1[k], a1);
                a2 = fmaf(bf2f(f2[k]), uw2[k], a2);
            }
        }
        for (; j < nb; ++j) {
            int s = __builtin_amdgcn_readlane(sl, j);
            float u0 = rl_f(w0, j), u1 = rl_f(w1, j), u2 = rl_f(w2, j);
            const unsigned short* xp = xf + (size_t)s * DD;
            a0 = fmaf(bf2f(xp[lane]),       u0, a0);
            a1 = fmaf(bf2f(xp[64 + lane]),  u1, a1);
            a2 = fmaf(bf2f(xp[128 + lane]), u2, a2);
        }
    }
    float o0 = a0 / (den0 + 1e-16f);
    float o1 = a1 / (den1 + 1e-16f);
    float o2 = a2 / (den2 + 1e-16f);
    size_t o = (size_t)d * DD + lane;
    outp[o]       = o0;
    outp[o + 64]  = o1;
    outp[o + 128] = o2;

    // ---- fused BN stats: block reduce + 64-slot atomics ----
    float y0 = fmaxf(o0 + bias[lane],       0.f);
    float y1 = fmaxf(o1 + bias[64 + lane],  0.f);
    float y2 = fmaxf(o2 + bias[128 + lane], 0.f);
    bs1[wid][lane]       = y0;  bs2[wid][lane]       = y0 * y0;
    bs1[wid][lane + 64]  = y1;  bs2[wid][lane + 64]  = y1 * y1;
    bs1[wid][lane + 128] = y2;  bs2[wid][lane + 128] = y2 * y2;
    __syncthreads();
    const int tid = threadIdx.x;
    if (tid < DD) {
        float t1 = bs1[0][tid] + bs1[1][tid] + bs1[2][tid] + bs1[3][tid];
        float t2 = bs2[0][tid] + bs2[1][tid] + bs2[2][tid] + bs2[3][tid];
        int slot = blockIdx.x & (NSLOT - 1);
        atomicAdd(&sb1[slot * DD + tid], t1);
        atomicAdd(&sb2[slot * DD + tid], t2);
    }
}

// ---- collapse 64 slot-buffers -> S1/S2 (1 block, 192 threads) ----
__global__ void bn_reduce(const float* __restrict__ sb1, const float* __restrict__ sb2,
                          float* __restrict__ s1, float* __restrict__ s2) {
    int j = threadIdx.x;
    float a = 0.f, q = 0.f;
    for (int s = 0; s < NSLOT; ++s) {
        a += sb1[s * DD + j];
        q += sb2[s * DD + j];
    }
    s1[j] = a;
    s2[j] = q;
}

extern "C" void kernel_launch(void* const* d_in, const int* in_sizes, int n_in,
                              void* d_out, int out_size, void* d_ws, size_t ws_size,
                              hipStream_t stream) {
    const float* x   = (const float*)d_in[0];
    const float* W1  = (const float*)d_in[1];
    const float* as1 = (const float*)d_in[2];
    const float* ad1 = (const float*)d_in[3];
    const float* b1  = (const float*)d_in[4];
    const float* g1  = (const float*)d_in[5];
    const float* be1 = (const float*)d_in[6];
    const float* W2  = (const float*)d_in[7];
    const float* as2 = (const float*)d_in[8];
    const float* ad2 = (const float*)d_in[9];
    const float* b2  = (const float*)d_in[10];
    const float* g2  = (const float*)d_in[11];
    const float* be2 = (const float*)d_in[12];
    const float* Wf  = (const float*)d_in[13];
    const float* bf  = (const float*)d_in[14];
    const int*   ei  = (const int*)d_in[15];
    const int* src = ei;
    const int* dst = ei + NE;
    float* out = (float*)d_out;

    float* ws = (float*)d_ws;
    float* CB1 = ws;                          // [N,192]
    float* CB2 = CB1 + (size_t)NN * DD;       // [N,192]
    float4* AS4 = (float4*)(CB2 + (size_t)NN * DD);   // [N] float4
    float4* AD4 = AS4 + NN;                   // [N] float4
    int* DEG   = (int*)(AD4 + NN);            // [N]  -- memset covers DEG..SB2b
    float* SB1a = (float*)(DEG + NN);         // [64][192] slot stats, layer 1
    float* SB2a = SB1a + NSLOT * DD;
    float* SB1b = SB2a + NSLOT * DD;          // layer 2
    float* SB2b = SB1b + NSLOT * DD;
    float* S1a = SB2b + NSLOT * DD;           // [192] final stats (written by bn_reduce)
    float* S2a = S1a + DD;
    float* S1b = S2a + DD;
    float* S2b = S1b + DD;
    int* ROWPTR = (int*)(S2b + DD);           // [N+1]
    int* CURSOR = ROWPTR + NN + 1;            // [N]
    int* BSUM   = CURSOR + NN;                // [NB]
    int* BOFF   = BSUM + NB;                  // [NB]
    int* CSRS   = BOFF + NB;                  // [E]
    unsigned short* R    = (unsigned short*)(CSRS + NE);
    unsigned short* Abf  = R;                          // [N,192] bf16 features
    unsigned short* W1hT = Abf + (size_t)NN * DD;      // [192,256]
    unsigned short* W2hT = W1hT + DIN * DD;            // [192,192]
    unsigned short* WfhT = W2hT + DD * DD;             // [64,192]

    const int edge_grid = (NE + 255) / 256;
    const int gemm_grid = (NN + 63) / 64;
    const int gat_grid  = NN / 4;             // 12500 exact (NN % 4 == 0)
    const int wsp_grid  = (W1G + W2G + WFG + 255) / 256;

    // ---- one memset: DEG + four slot-stat buffers (contiguous) ----
    hipMemsetAsync(DEG, 0, (size_t)NN * 4 + 4 * NSLOT * DD * 4, stream);

    // ---- CSR build (once) ----
    hist_kernel<<<edge_grid, 256, 0, stream>>>(dst, DEG, NE);
    blocksum_kernel<<<NB, 256, 0, stream>>>(DEG, BSUM);
    scan_bsums<<<1, 256, 0, stream>>>(BSUM, BOFF, ROWPTR);
    expand_kernel<<<NB, 256, 0, stream>>>(DEG, BOFF, ROWPTR, CURSOR);
    scatter_kernel<<<edge_grid, 256, 0, stream>>>(src, dst, CURSOR, CSRS, NE);

    // ---- weight conversion ----
    wsplit_all<<<wsp_grid, 256, 0, stream>>>(W1, W2, Wf, W1hT, W2hT, WfhT);

    // ================= layer 1 (dots fused; stats fused in gat) =================
    mfma_gemm<DIN, DD, 0, true><<<gemm_grid, 256, 0, stream>>>(
        x, nullptr,
        nullptr, nullptr, nullptr, nullptr, nullptr,
        nullptr, nullptr, nullptr, nullptr, nullptr,
        W1hT, as1, ad1, AS4, AD4, nullptr, nullptr, Abf, NN);
    gat_gather<<<gat_grid, 256, 0, stream>>>(Abf, AS4, AD4, ROWPTR, CSRS,
                                             b1, SB1a, SB2a, CB1);
    bn_reduce<<<1, DD, 0, stream>>>(SB1a, SB2a, S1a, S2a);

    // ================= layer 2 (BN1 per-block + dots fused) =================
    mfma_gemm<DD, DD, 1, true><<<gemm_grid, 256, 0, stream>>>(
        CB1, nullptr,
        b1, S1a, S2a, g1, be1,
        nullptr, nullptr, nullptr, nullptr, nullptr,
        W2hT, as2, ad2, AS4, AD4, nullptr, nullptr, Abf, NN);
    gat_gather<<<gat_grid, 256, 0, stream>>>(Abf, AS4, AD4, ROWPTR, CSRS,
                                             b2, SB1b, SB2b, CB2);
    bn_reduce<<<1, DD, 0, stream>>>(SB1b, SB2b, S1b, S2b);

    // ====== final: out = (bn1(h1) + bn2(h2)) @ Wf + bf (BN per-block in staging) ======
    mfma_gemm<DD, DF, 2, false><<<gemm_grid, 256, 0, stream>>>(
        CB1, CB2,
        b1, S1a, S2a, g1, be1,
        b2, S1b, S2b, g2, be2,
        WfhT, nullptr, nullptr, nullptr, nullptr, bf, out, nullptr, NN);
}